// Round 14
// baseline (64.974 us; speedup 1.0000x reference)
//
#include <hip/hip_runtime.h>

// ---------------------------------------------------------------------------
// cross_entropy_with_hnm_for_one_class_detection
//
// 3 scales: softmax-CE with hard-negative mining (k-th order statistic of
// neg_prob over N=B*H*W) + masked bbox MSE. Output: 3 floats.
//
// R13 was the best structure (recompute > round-trip, no fences, count-only
// hist in pass1). R14 isolates ONE knob: grid TLP. pass1/cand move from
// 525 blocks x 8 elem/thread (2.05 blk/CU, 8 waves/CU) to 1050 blocks x
// 4 elem/thread (4.1 blk/CU, 16 waves/CU). Everything else unchanged.
//   k_zero -> k_pass1 -> k_cand -> k_select.
// ---------------------------------------------------------------------------

namespace {
constexpr int HW0 = 25600, HW1 = 6400, HW2 = 1600;
constexpr int N0 = 32 * HW0;  // 819200
constexpr int N1 = 32 * HW1;  // 204800
constexpr int N2 = 32 * HW2;  // 51200

constexpr int LBINS = 256;
constexpr int CAP = 8192;  // candidate capacity per scale

// 1024 elements per block (one float4-quad per thread)
constexpr int B0 = N0 / 1024, B1 = N1 / 1024, B2 = N2 / 1024;  // 800,200,50
constexpr int NBLK = B0 + B1 + B2;                             // 1050

__device__ __forceinline__ void scale_of(int bid, int& s, int& rel, int& lo,
                                         int& hi) {
  if (bid < B0) {
    s = 0; rel = bid; lo = 0; hi = B0;
  } else if (bid < B0 + B1) {
    s = 1; rel = bid - B0; lo = B0; hi = B0 + B1;
  } else {
    s = 2; rel = bid - B0 - B1; lo = B0 + B1; hi = NBLK;
  }
}

__device__ __forceinline__ unsigned int lin_bin(float v) {
  unsigned int b = (unsigned int)(v * 256.0f);
  return b > 255u ? 255u : b;
}
}  // namespace

// ---------------- pass 0: zero control region (~3.3 KB) ---------------------
__global__ __launch_bounds__(256) void k_zero(uint4* __restrict__ p, int n4) {
  for (int i = threadIdx.x; i < n4; i += 256) p[i] = make_uint4(0u, 0u, 0u, 0u);
}

// ------- pass 1: softmax stats, counts, pos-CE, bbox, count hist ------------
template <int HW>
__device__ void p1_main(int rel, const float* __restrict__ sc,
                        const float* __restrict__ bb,
                        const float* __restrict__ gl,
                        unsigned int* __restrict__ histS,
                        double* __restrict__ posce_o,
                        double* __restrict__ diff2_o,
                        unsigned int* __restrict__ pcnt_o,
                        unsigned int* __restrict__ ncnt_o) {
  __shared__ unsigned int lh[4][LBINS];  // wave-private count hists, 4 KiB
  const int tid = threadIdx.x, wid = tid >> 6;
#pragma unroll
  for (int w = 0; w < 4; ++w) lh[w][tid] = 0u;
  __syncthreads();

  // one quad; all 4 coalesced loads issued before any math
  const int q0 = (rel * 256 + tid) * 4;
  const int bA = q0 / HW, hwA = q0 - bA * HW;
  const float* scA = sc + (size_t)bA * 2 * HW + hwA;
  const float* glA = gl + (size_t)bA * 6 * HW + hwA;
  const float4 s0A = *(const float4*)scA;
  const float4 s1A = *(const float4*)(scA + HW);
  const float4 l0A = *(const float4*)glA;
  const float4 l1A = *(const float4*)(glA + HW);

  double posce = 0.0, diff2 = 0.0;
  unsigned int pcnt = 0, ncnt = 0;
  {
    const float* bbq = bb + (size_t)bA * 4 * HW + hwA;
    const float s0a[4] = {s0A.x, s0A.y, s0A.z, s0A.w};
    const float s1a[4] = {s1A.x, s1A.y, s1A.z, s1A.w};
    const float l0a[4] = {l0A.x, l0A.y, l0A.z, l0A.w};
    const float l1a[4] = {l1A.x, l1A.y, l1A.z, l1A.w};
#pragma unroll
    for (int j = 0; j < 4; ++j) {
      const float d = s1a[j] - s0a[j];
      const float t = expf(-fabsf(d));
      const float l1p = log1pf(t);  // lse after max-sub
      const bool pos = l0a[j] > 0.5f;
      const bool neg = l1a[j] > 0.5f;
      const float sm1 = ((d >= 0.0f) ? 1.0f : t) / (1.0f + t);
      const float v = neg ? sm1 : 0.0f;
      atomicAdd(&lh[wid][lin_bin(v)], 1u);
      if (neg) ncnt++;
      if (pos) {
        pcnt++;
        posce += (double)(-l0a[j] * (((d > 0.0f) ? -d : 0.0f) - l1p));
        float acc = 0.0f;
#pragma unroll
        for (int c = 0; c < 4; ++c) {
          const float dd = glA[(2 + c) * HW + j] - bbq[c * HW + j];
          acc += dd * dd;
        }
        diff2 += (double)acc;
      }
    }
  }

  __syncthreads();
  {  // flush counts: one bin per thread
    const unsigned int c = lh[0][tid] + lh[1][tid] + lh[2][tid] + lh[3][tid];
    if (c) atomicAdd(&histS[tid], c);
  }

  // reduce partials -> per-block SoA slots (no global atomics)
  for (int o = 32; o > 0; o >>= 1) {
    posce += __shfl_down(posce, o, 64);
    diff2 += __shfl_down(diff2, o, 64);
    pcnt += __shfl_down(pcnt, o, 64);
    ncnt += __shfl_down(ncnt, o, 64);
  }
  __shared__ double wa[4], wb[4];
  __shared__ unsigned int wc[4], wd[4];
  if ((tid & 63) == 0) {
    wa[wid] = posce; wb[wid] = diff2; wc[wid] = pcnt; wd[wid] = ncnt;
  }
  __syncthreads();
  if (tid == 0) {
    *posce_o = wa[0] + wa[1] + wa[2] + wa[3];
    *diff2_o = wb[0] + wb[1] + wb[2] + wb[3];
    *pcnt_o = wc[0] + wc[1] + wc[2] + wc[3];
    *ncnt_o = wd[0] + wd[1] + wd[2] + wd[3];
  }
}

__global__ __launch_bounds__(256) void k_pass1(
    const float* sc0, const float* bb0, const float* gl0,
    const float* sc1, const float* bb1, const float* gl1,
    const float* sc2, const float* bb2, const float* gl2,
    unsigned int* hist, double* posce_a, double* diff2_a,
    unsigned int* pcnt_a, unsigned int* ncnt_a) {
  int s, rel, lo, hi;
  scale_of(blockIdx.x, s, rel, lo, hi);
  const int bid = blockIdx.x;
  if (s == 0)
    p1_main<HW0>(rel, sc0, bb0, gl0, hist, posce_a + bid, diff2_a + bid,
                 pcnt_a + bid, ncnt_a + bid);
  else if (s == 1)
    p1_main<HW1>(rel, sc1, bb1, gl1, hist + LBINS, posce_a + bid,
                 diff2_a + bid, pcnt_a + bid, ncnt_a + bid);
  else
    p1_main<HW2>(rel, sc2, bb2, gl2, hist + 2 * LBINS, posce_a + bid,
                 diff2_a + bid, pcnt_a + bid, ncnt_a + bid);
}

// --- pass 2: recompute v; ce-below partial; gather in-bin candidates --------
template <int HW>
__device__ void p2_main(int rel, int s, int lo, int hi,
                        const float* __restrict__ sc,
                        const float* __restrict__ gl,
                        const unsigned int* __restrict__ pcnt_a,
                        const unsigned int* __restrict__ ncnt_a,
                        const unsigned int* __restrict__ hist,
                        double* __restrict__ ceb_o,
                        unsigned int* __restrict__ cand_cnt,
                        unsigned int* __restrict__ cand) {
  const int tid = threadIdx.x;

  // issue the 3 bulk loads first; they stay in flight across the scan
  const int q0 = (rel * 256 + tid) * 4;
  const int bA = q0 / HW, hwA = q0 - bA * HW;
  const float* scA = sc + (size_t)bA * 2 * HW + hwA;
  const float4 s0A = *(const float4*)scA;
  const float4 s1A = *(const float4*)(scA + HW);
  const float4 l1A = *(const float4*)(gl + (size_t)bA * 6 * HW + HW + hwA);

  // redundant count reduce (L2-hot, ~8 KB)
  __shared__ unsigned int sua[256], sub[256];
  {
    unsigned int c = 0, d = 0;
    for (int i = lo + tid; i < hi; i += 256) {
      c += pcnt_a[i];
      d += ncnt_a[i];
    }
    sua[tid] = c; sub[tid] = d;
  }
  __syncthreads();
  for (int o = 128; o > 0; o >>= 1) {
    if (tid < o) { sua[tid] += sua[tid + o]; sub[tid] += sub[tid + o]; }
    __syncthreads();
  }
  __shared__ unsigned int sh_k;
  if (tid == 0) {
    const unsigned long long k10 = 10ull * (unsigned long long)sua[0];
    sh_k = (k10 < (unsigned long long)sub[0]) ? (unsigned int)k10 : sub[0];
  }
  __syncthreads();

  // count-only 256-bin scan -> sel_bin
  __shared__ unsigned int partC[256];
  __shared__ unsigned int sh_selb;
  const unsigned int ownC = hist[s * LBINS + tid];
  partC[tid] = ownC;
  __syncthreads();
  for (int o = 1; o < 256; o <<= 1) {
    const unsigned int aC = (tid >= o) ? partC[tid - o] : 0u;
    __syncthreads();
    partC[tid] += aC;
    __syncthreads();
  }
  {
    const unsigned int k = sh_k;
    const unsigned int inclC = partC[tid];
    const unsigned int exclC = inclC - ownC;
    if (ownC && k >= exclC && k < inclC) sh_selb = (unsigned int)tid;
  }
  __syncthreads();

  // recompute v (bitwise == pass1), sum ce for bins < selb, gather in-bin
  __shared__ unsigned int cbuf[512];
  __shared__ unsigned int ccnt, cbase;
  if (tid == 0) ccnt = 0u;
  __syncthreads();
  const unsigned int bsel = sh_selb;
  double ceb = 0.0;
  {
    const float s0a[4] = {s0A.x, s0A.y, s0A.z, s0A.w};
    const float s1a[4] = {s1A.x, s1A.y, s1A.z, s1A.w};
    const float l1a[4] = {l1A.x, l1A.y, l1A.z, l1A.w};
#pragma unroll
    for (int j = 0; j < 4; ++j) {
      const float d = s1a[j] - s0a[j];
      const bool neg = l1a[j] > 0.5f;
      if (!neg) continue;  // v = 0: bin 0; ce contribution 0 either way
      const float t = expf(-fabsf(d));
      const float v = ((d >= 0.0f) ? 1.0f : t) / (1.0f + t);
      const unsigned int bin = lin_bin(v);
      if (bin < bsel) {
        ceb += (double)(log1pf(t) - ((d >= 0.0f) ? 0.0f : d));
      } else if (bin == bsel) {
        const unsigned int sl = atomicAdd(&ccnt, 1u);
        if (sl < 512u) {
          cbuf[sl] = __float_as_uint(v);
        } else {  // overflow fallback (rare)
          const unsigned int g2 = atomicAdd(&cand_cnt[s], 1u);
          if (g2 < (unsigned)CAP) cand[s * CAP + g2] = __float_as_uint(v);
        }
      }
    }
  }
  __syncthreads();
  if (tid == 0) {
    const unsigned int n = min(ccnt, 512u);
    cbase = n ? atomicAdd(&cand_cnt[s], n) : 0u;
  }
  __syncthreads();
  {
    const unsigned int n = min(ccnt, 512u);
    for (unsigned int i = tid; i < n; i += 256) {
      const unsigned int idx = cbase + i;
      if (idx < (unsigned)CAP) cand[s * CAP + idx] = cbuf[i];
    }
  }

  // reduce ceb -> per-block slot
  for (int o = 32; o > 0; o >>= 1) ceb += __shfl_down(ceb, o, 64);
  __shared__ double wv[4];
  if ((tid & 63) == 0) wv[tid >> 6] = ceb;
  __syncthreads();
  if (tid == 0) *ceb_o = wv[0] + wv[1] + wv[2] + wv[3];
}

__global__ __launch_bounds__(256) void k_cand(
    const float* sc0, const float* gl0, const float* sc1, const float* gl1,
    const float* sc2, const float* gl2,
    const unsigned int* __restrict__ pcnt_a,
    const unsigned int* __restrict__ ncnt_a,
    const unsigned int* __restrict__ hist, double* __restrict__ ceb_a,
    unsigned int* __restrict__ cand_cnt, unsigned int* __restrict__ cand) {
  int s, rel, lo, hi;
  scale_of(blockIdx.x, s, rel, lo, hi);
  const int bid = blockIdx.x;
  if (s == 0)
    p2_main<HW0>(rel, 0, lo, hi, sc0, gl0, pcnt_a, ncnt_a, hist, ceb_a + bid,
                 cand_cnt, cand);
  else if (s == 1)
    p2_main<HW1>(rel, 1, lo, hi, sc1, gl1, pcnt_a, ncnt_a, hist, ceb_a + bid,
                 cand_cnt, cand);
  else
    p2_main<HW2>(rel, 2, lo, hi, sc2, gl2, pcnt_a, ncnt_a, hist, ceb_a + bid,
                 cand_cnt, cand);
}

// ------- pass 3: 3 blocks -- reduce + scan + radix select + finalize --------
__global__ __launch_bounds__(256) void k_select(
    const double* __restrict__ posce_a, const double* __restrict__ diff2_a,
    const double* __restrict__ ceb_a, const unsigned int* __restrict__ pcnt_a,
    const unsigned int* __restrict__ ncnt_a,
    const unsigned int* __restrict__ hist,
    const unsigned int* __restrict__ cand_cnt,
    const unsigned int* __restrict__ cand, float* __restrict__ out) {
  const int s = blockIdx.x;
  const int tid = threadIdx.x;
  const int lo = (s == 0) ? 0 : (s == 1) ? B0 : B0 + B1;
  const int hi = (s == 0) ? B0 : (s == 1) ? B0 + B1 : NBLK;

  __shared__ double sda[256], sdb[256], sdc[256];
  __shared__ unsigned int sua[256], sub[256];
  {
    double a = 0.0, b2 = 0.0, e = 0.0;
    unsigned int c = 0, d = 0;
    for (int i = lo + tid; i < hi; i += 256) {
      a += posce_a[i]; b2 += diff2_a[i]; e += ceb_a[i];
      c += pcnt_a[i];  d += ncnt_a[i];
    }
    sda[tid] = a; sdb[tid] = b2; sdc[tid] = e; sua[tid] = c; sub[tid] = d;
  }
  __syncthreads();
  for (int o = 128; o > 0; o >>= 1) {
    if (tid < o) {
      sda[tid] += sda[tid + o]; sdb[tid] += sdb[tid + o];
      sdc[tid] += sdc[tid + o];
      sua[tid] += sua[tid + o]; sub[tid] += sub[tid + o];
    }
    __syncthreads();
  }
  __shared__ double sh_posce, sh_diff2, sh_ceb;
  __shared__ unsigned int sh_pcnt, sh_k;
  if (tid == 0) {
    sh_posce = sda[0];
    sh_diff2 = sdb[0];
    sh_ceb = sdc[0];
    sh_pcnt = sua[0];
    const unsigned long long k10 = 10ull * (unsigned long long)sua[0];
    sh_k = (k10 < (unsigned long long)sub[0]) ? (unsigned int)k10 : sub[0];
  }
  __syncthreads();

  // count-only 256-bin scan -> selb, selr
  __shared__ unsigned int partC[256];
  __shared__ unsigned int sh_selb, sh_selr;
  const unsigned int ownC = hist[s * LBINS + tid];
  partC[tid] = ownC;
  __syncthreads();
  for (int o = 1; o < 256; o <<= 1) {
    const unsigned int aC = (tid >= o) ? partC[tid - o] : 0u;
    __syncthreads();
    partC[tid] += aC;
    __syncthreads();
  }
  {
    const unsigned int k = sh_k;
    const unsigned int inclC = partC[tid];
    const unsigned int exclC = inclC - ownC;
    if (ownC && k >= exclC && k < inclC) {
      sh_selb = (unsigned int)tid;
      sh_selr = k - exclC;
    }
  }
  __syncthreads();

  // exact radix select over candidates
  const unsigned int n = min(cand_cnt[s], (unsigned int)CAP);
  const unsigned int* lst = cand + s * CAP;
  __shared__ unsigned int dh[256];
  __shared__ unsigned int shp, shr, sh_w8, sh_nr;
  if (tid == 0) {
    shr = sh_selr;
    // bins >=1 span one binade -> candidates share bits 31:24
    shp = (sh_selb >= 1u) ? (lst[0] & 0xFF000000u) : 0u;
  }
  __syncthreads();
  const int r0 = (sh_selb >= 1u) ? 1 : 0;
  for (int round = r0; round < 4; ++round) {
    const int shift = 24 - 8 * round;
    dh[tid] = 0u;
    __syncthreads();
    const unsigned int pref = shp;
    for (unsigned int i = tid; i < n; i += 256) {
      const unsigned int v = lst[i];
      const bool match =
          (round == 0) || ((v >> (shift + 8)) == (pref >> (shift + 8)));
      if (match) atomicAdd(&dh[(v >> shift) & 255u], 1u);
    }
    __syncthreads();
    const unsigned int own = dh[tid];
    for (int o = 1; o < 256; o <<= 1) {  // inclusive scan in place
      const unsigned int add = (tid >= o) ? dh[tid - o] : 0u;
      __syncthreads();
      dh[tid] += add;
      __syncthreads();
    }
    const unsigned int incl = dh[tid];
    const unsigned int excl = incl - own;
    const unsigned int k = shr;
    if (own && k >= excl && k < incl) {
      sh_w8 = (unsigned int)tid;
      sh_nr = k - excl;
    }
    __syncthreads();
    if (tid == 0) {
      shp = pref | (sh_w8 << shift);
      shr = sh_nr;
    }
    __syncthreads();
  }
  const float thr = __uint_as_float(shp);

  // in-bin CE: candidates with 0 < v <= thr
  double acc = 0.0;
  for (unsigned int i = tid; i < n; i += 256) {
    const float v = __uint_as_float(lst[i]);
    if (v > 0.0f && v <= thr) acc += (double)(-logf(v));
  }
  sda[tid] = acc;
  __syncthreads();
  for (int o = 128; o > 0; o >>= 1) {
    if (tid < o) sda[tid] += sda[tid + o];
    __syncthreads();
  }
  if (tid == 0) {
    const double Ns = (s == 0) ? (double)N0 : (s == 1) ? (double)N1 : (double)N2;
    const double W = (s == 0) ? 160.0 : (s == 1) ? 80.0 : 40.0;
    const double ls = (sh_posce + sh_ceb + sda[0]) / (2.0 * Ns);
    const double lb = (sh_diff2 / W) / (4.0 * (double)sh_pcnt);
    out[s] = (float)(ls + lb);
  }
}

extern "C" void kernel_launch(void* const* d_in, const int* in_sizes, int n_in,
                              void* d_out, int out_size, void* d_ws,
                              size_t ws_size, hipStream_t stream) {
  const float* sc0 = (const float*)d_in[0];
  const float* bb0 = (const float*)d_in[1];
  const float* gl0 = (const float*)d_in[3];
  const float* sc1 = (const float*)d_in[4];
  const float* bb1 = (const float*)d_in[5];
  const float* gl1 = (const float*)d_in[7];
  const float* sc2 = (const float*)d_in[8];
  const float* bb2 = (const float*)d_in[9];
  const float* gl2 = (const float*)d_in[11];

  char* ws = (char*)d_ws;
  unsigned int* hist = (unsigned int*)ws;              // 3*256 u32
  unsigned int* cand_cnt = hist + 3 * LBINS;           // 4 u32
  size_t zbytes = (size_t)3 * LBINS * 4 + 16;          // zeroed region
  zbytes = (zbytes + 255) & ~(size_t)255;
  size_t off = zbytes;
  double* posce_a = (double*)(ws + off);  off += (size_t)NBLK * 8;
  double* diff2_a = (double*)(ws + off);  off += (size_t)NBLK * 8;
  double* ceb_a = (double*)(ws + off);    off += (size_t)NBLK * 8;
  unsigned int* pcnt_a = (unsigned int*)(ws + off);  off += (size_t)NBLK * 4;
  unsigned int* ncnt_a = (unsigned int*)(ws + off);  off += (size_t)NBLK * 4;
  off = (off + 255) & ~(size_t)255;
  unsigned int* cand = (unsigned int*)(ws + off);      // 3*CAP u32

  const dim3 blk(256);
  k_zero<<<dim3(1), blk, 0, stream>>>((uint4*)d_ws, (int)(zbytes >> 4));
  k_pass1<<<dim3(NBLK), blk, 0, stream>>>(sc0, bb0, gl0, sc1, bb1, gl1, sc2,
                                          bb2, gl2, hist, posce_a, diff2_a,
                                          pcnt_a, ncnt_a);
  k_cand<<<dim3(NBLK), blk, 0, stream>>>(sc0, gl0, sc1, gl1, sc2, gl2, pcnt_a,
                                         ncnt_a, hist, ceb_a, cand_cnt, cand);
  k_select<<<dim3(3), blk, 0, stream>>>(posce_a, diff2_a, ceb_a, pcnt_a,
                                        ncnt_a, hist, cand_cnt, cand,
                                        (float*)d_out);
}

// Round 15
// 50.774 us; speedup vs baseline: 1.2797x; 1.2797x over previous
//
#include <hip/hip_runtime.h>

// ---------------------------------------------------------------------------
// cross_entropy_with_hnm_for_one_class_detection
//
// 3 scales: softmax-CE with hard-negative mining (k-th order statistic of
// neg_prob over N=B*H*W) + masked bbox MSE. Output: 3 floats.
//
// R13 structure (proven 54us): 525 blocks x 8 elem/thread, count-only hist
// in pass1, k_cand recomputes v bitwise-identically (recompute > round-trip),
// no fences, 4 launches. R15 shaves per-element cost:
//  - gt_label[:,1] == 1 - gt_label[:,0] exactly -> drop the l1 stream
//    (saves 4.3 MB) and the l0/l1 multiplies.
//  - log1pf -> __logf(1+t), expf -> __expf (same formula in both passes ->
//    binning stays consistent; error ~1e-7 << 5.2e-3 threshold).
// ---------------------------------------------------------------------------

namespace {
constexpr int HW0 = 25600, HW1 = 6400, HW2 = 1600;
constexpr int N0 = 32 * HW0;  // 819200
constexpr int N1 = 32 * HW1;  // 204800
constexpr int N2 = 32 * HW2;  // 51200

constexpr int LBINS = 256;
constexpr int CAP = 8192;  // candidate capacity per scale

// 2048 elements per block (two float4-quads per thread)
constexpr int B0 = N0 / 2048, B1 = N1 / 2048, B2 = N2 / 2048;  // 400,100,25
constexpr int NBLK = B0 + B1 + B2;                             // 525

__device__ __forceinline__ void scale_of(int bid, int& s, int& rel, int& lo,
                                         int& hi) {
  if (bid < B0) {
    s = 0; rel = bid; lo = 0; hi = B0;
  } else if (bid < B0 + B1) {
    s = 1; rel = bid - B0; lo = B0; hi = B0 + B1;
  } else {
    s = 2; rel = bid - B0 - B1; lo = B0 + B1; hi = NBLK;
  }
}

__device__ __forceinline__ unsigned int lin_bin(float v) {
  unsigned int b = (unsigned int)(v * 256.0f);
  return b > 255u ? 255u : b;
}
}  // namespace

// ---------------- pass 0: zero control region (~3.3 KB) ---------------------
__global__ __launch_bounds__(256) void k_zero(uint4* __restrict__ p, int n4) {
  for (int i = threadIdx.x; i < n4; i += 256) p[i] = make_uint4(0u, 0u, 0u, 0u);
}

// ------- pass 1: softmax stats, counts, pos-CE, bbox, count hist ------------
template <int HW>
__device__ void p1_main(int rel, const float* __restrict__ sc,
                        const float* __restrict__ bb,
                        const float* __restrict__ gl,
                        unsigned int* __restrict__ histS,
                        double* __restrict__ posce_o,
                        double* __restrict__ diff2_o,
                        unsigned int* __restrict__ pcnt_o,
                        unsigned int* __restrict__ ncnt_o) {
  __shared__ unsigned int lh[4][LBINS];  // wave-private count hists, 4 KiB
  const int tid = threadIdx.x, wid = tid >> 6;
#pragma unroll
  for (int w = 0; w < 4; ++w) lh[w][tid] = 0u;
  __syncthreads();

  // two quad-groups; all coalesced loads issued before any math
  const int q0 = (rel * 512 + tid) * 4;
  const int q1 = q0 + 1024;
  const int bA = q0 / HW, hwA = q0 - bA * HW;
  const int bB = q1 / HW, hwB = q1 - bB * HW;
  const float* scA = sc + (size_t)bA * 2 * HW + hwA;
  const float* scB = sc + (size_t)bB * 2 * HW + hwB;
  const float* glA = gl + (size_t)bA * 6 * HW + hwA;
  const float* glB = gl + (size_t)bB * 6 * HW + hwB;
  const float4 s0A = *(const float4*)scA;
  const float4 s1A = *(const float4*)(scA + HW);
  const float4 l0A = *(const float4*)glA;  // pos flag; neg = !pos (l1 == 1-l0)
  const float4 s0B = *(const float4*)scB;
  const float4 s1B = *(const float4*)(scB + HW);
  const float4 l0B = *(const float4*)glB;

  double posce = 0.0, diff2 = 0.0;
  unsigned int pcnt = 0, ncnt = 0;

  auto process = [&](const float4& s0v, const float4& s1v, const float4& l0v,
                     const float* __restrict__ glq,
                     const float* __restrict__ bbq) {
    const float s0a[4] = {s0v.x, s0v.y, s0v.z, s0v.w};
    const float s1a[4] = {s1v.x, s1v.y, s1v.z, s1v.w};
    const float l0a[4] = {l0v.x, l0v.y, l0v.z, l0v.w};
#pragma unroll
    for (int j = 0; j < 4; ++j) {
      const float d = s1a[j] - s0a[j];
      const float t = __expf(-fabsf(d));
      const float l1p = __logf(1.0f + t);  // lse after max-sub
      const bool pos = l0a[j] > 0.5f;
      const float sm1 = ((d >= 0.0f) ? 1.0f : t) / (1.0f + t);
      const float v = pos ? 0.0f : sm1;
      atomicAdd(&lh[wid][lin_bin(v)], 1u);
      if (pos) {
        pcnt++;
        posce += (double)(l1p + ((d > 0.0f) ? d : 0.0f));  // = -ls0
        float acc = 0.0f;
#pragma unroll
        for (int c = 0; c < 4; ++c) {
          const float dd = glq[(2 + c) * HW + j] - bbq[c * HW + j];
          acc += dd * dd;
        }
        diff2 += (double)acc;
      } else {
        ncnt++;
      }
    }
  };
  process(s0A, s1A, l0A, glA, bb + (size_t)bA * 4 * HW + hwA);
  process(s0B, s1B, l0B, glB, bb + (size_t)bB * 4 * HW + hwB);

  __syncthreads();
  {  // flush counts: one bin per thread
    const unsigned int c = lh[0][tid] + lh[1][tid] + lh[2][tid] + lh[3][tid];
    if (c) atomicAdd(&histS[tid], c);
  }

  // reduce partials -> per-block SoA slots (no global atomics)
  for (int o = 32; o > 0; o >>= 1) {
    posce += __shfl_down(posce, o, 64);
    diff2 += __shfl_down(diff2, o, 64);
    pcnt += __shfl_down(pcnt, o, 64);
    ncnt += __shfl_down(ncnt, o, 64);
  }
  __shared__ double wa[4], wb[4];
  __shared__ unsigned int wc[4], wd[4];
  if ((tid & 63) == 0) {
    wa[wid] = posce; wb[wid] = diff2; wc[wid] = pcnt; wd[wid] = ncnt;
  }
  __syncthreads();
  if (tid == 0) {
    *posce_o = wa[0] + wa[1] + wa[2] + wa[3];
    *diff2_o = wb[0] + wb[1] + wb[2] + wb[3];
    *pcnt_o = wc[0] + wc[1] + wc[2] + wc[3];
    *ncnt_o = wd[0] + wd[1] + wd[2] + wd[3];
  }
}

__global__ __launch_bounds__(256) void k_pass1(
    const float* sc0, const float* bb0, const float* gl0,
    const float* sc1, const float* bb1, const float* gl1,
    const float* sc2, const float* bb2, const float* gl2,
    unsigned int* hist, double* posce_a, double* diff2_a,
    unsigned int* pcnt_a, unsigned int* ncnt_a) {
  int s, rel, lo, hi;
  scale_of(blockIdx.x, s, rel, lo, hi);
  const int bid = blockIdx.x;
  if (s == 0)
    p1_main<HW0>(rel, sc0, bb0, gl0, hist, posce_a + bid, diff2_a + bid,
                 pcnt_a + bid, ncnt_a + bid);
  else if (s == 1)
    p1_main<HW1>(rel, sc1, bb1, gl1, hist + LBINS, posce_a + bid,
                 diff2_a + bid, pcnt_a + bid, ncnt_a + bid);
  else
    p1_main<HW2>(rel, sc2, bb2, gl2, hist + 2 * LBINS, posce_a + bid,
                 diff2_a + bid, pcnt_a + bid, ncnt_a + bid);
}

// --- pass 2: recompute v; ce-below partial; gather in-bin candidates --------
template <int HW>
__device__ void p2_main(int rel, int s, int lo, int hi,
                        const float* __restrict__ sc,
                        const float* __restrict__ gl,
                        const unsigned int* __restrict__ pcnt_a,
                        const unsigned int* __restrict__ ncnt_a,
                        const unsigned int* __restrict__ hist,
                        double* __restrict__ ceb_o,
                        unsigned int* __restrict__ cand_cnt,
                        unsigned int* __restrict__ cand) {
  const int tid = threadIdx.x;

  // issue the 6 bulk loads first; they stay in flight across the scan
  const int q0 = (rel * 512 + tid) * 4;
  const int q1 = q0 + 1024;
  const int bA = q0 / HW, hwA = q0 - bA * HW;
  const int bB = q1 / HW, hwB = q1 - bB * HW;
  const float* scA = sc + (size_t)bA * 2 * HW + hwA;
  const float* scB = sc + (size_t)bB * 2 * HW + hwB;
  const float4 s0A = *(const float4*)scA;
  const float4 s1A = *(const float4*)(scA + HW);
  const float4 l0A = *(const float4*)(gl + (size_t)bA * 6 * HW + hwA);
  const float4 s0B = *(const float4*)scB;
  const float4 s1B = *(const float4*)(scB + HW);
  const float4 l0B = *(const float4*)(gl + (size_t)bB * 6 * HW + hwB);

  // redundant count reduce (L2-hot, ~4 KB)
  __shared__ unsigned int sua[256], sub[256];
  {
    unsigned int c = 0, d = 0;
    for (int i = lo + tid; i < hi; i += 256) {
      c += pcnt_a[i];
      d += ncnt_a[i];
    }
    sua[tid] = c; sub[tid] = d;
  }
  __syncthreads();
  for (int o = 128; o > 0; o >>= 1) {
    if (tid < o) { sua[tid] += sua[tid + o]; sub[tid] += sub[tid + o]; }
    __syncthreads();
  }
  __shared__ unsigned int sh_k;
  if (tid == 0) {
    const unsigned long long k10 = 10ull * (unsigned long long)sua[0];
    sh_k = (k10 < (unsigned long long)sub[0]) ? (unsigned int)k10 : sub[0];
  }
  __syncthreads();

  // count-only 256-bin scan -> sel_bin
  __shared__ unsigned int partC[256];
  __shared__ unsigned int sh_selb;
  const unsigned int ownC = hist[s * LBINS + tid];
  partC[tid] = ownC;
  __syncthreads();
  for (int o = 1; o < 256; o <<= 1) {
    const unsigned int aC = (tid >= o) ? partC[tid - o] : 0u;
    __syncthreads();
    partC[tid] += aC;
    __syncthreads();
  }
  {
    const unsigned int k = sh_k;
    const unsigned int inclC = partC[tid];
    const unsigned int exclC = inclC - ownC;
    if (ownC && k >= exclC && k < inclC) sh_selb = (unsigned int)tid;
  }
  __syncthreads();

  // recompute v (bitwise == pass1), sum ce for bins < selb, gather in-bin
  __shared__ unsigned int cbuf[512];
  __shared__ unsigned int ccnt, cbase;
  if (tid == 0) ccnt = 0u;
  __syncthreads();
  const unsigned int bsel = sh_selb;
  double ceb = 0.0;

  auto scan8 = [&](const float4& s0v, const float4& s1v, const float4& l0v) {
    const float s0a[4] = {s0v.x, s0v.y, s0v.z, s0v.w};
    const float s1a[4] = {s1v.x, s1v.y, s1v.z, s1v.w};
    const float l0a[4] = {l0v.x, l0v.y, l0v.z, l0v.w};
#pragma unroll
    for (int j = 0; j < 4; ++j) {
      const float d = s1a[j] - s0a[j];
      if (l0a[j] > 0.5f) continue;  // pos: v = 0 -> bin 0; no neg-CE
      const float t = __expf(-fabsf(d));
      const float v = ((d >= 0.0f) ? 1.0f : t) / (1.0f + t);
      const unsigned int bin = lin_bin(v);
      if (bin < bsel) {
        ceb += (double)(__logf(1.0f + t) + ((d >= 0.0f) ? 0.0f : -d));
      } else if (bin == bsel) {
        const unsigned int sl = atomicAdd(&ccnt, 1u);
        if (sl < 512u) {
          cbuf[sl] = __float_as_uint(v);
        } else {  // overflow fallback (rare)
          const unsigned int g2 = atomicAdd(&cand_cnt[s], 1u);
          if (g2 < (unsigned)CAP) cand[s * CAP + g2] = __float_as_uint(v);
        }
      }
    }
  };
  scan8(s0A, s1A, l0A);
  scan8(s0B, s1B, l0B);
  __syncthreads();
  if (tid == 0) {
    const unsigned int n = min(ccnt, 512u);
    cbase = n ? atomicAdd(&cand_cnt[s], n) : 0u;
  }
  __syncthreads();
  {
    const unsigned int n = min(ccnt, 512u);
    for (unsigned int i = tid; i < n; i += 256) {
      const unsigned int idx = cbase + i;
      if (idx < (unsigned)CAP) cand[s * CAP + idx] = cbuf[i];
    }
  }

  // reduce ceb -> per-block slot
  for (int o = 32; o > 0; o >>= 1) ceb += __shfl_down(ceb, o, 64);
  __shared__ double wv[4];
  if ((tid & 63) == 0) wv[tid >> 6] = ceb;
  __syncthreads();
  if (tid == 0) *ceb_o = wv[0] + wv[1] + wv[2] + wv[3];
}

__global__ __launch_bounds__(256) void k_cand(
    const float* sc0, const float* gl0, const float* sc1, const float* gl1,
    const float* sc2, const float* gl2,
    const unsigned int* __restrict__ pcnt_a,
    const unsigned int* __restrict__ ncnt_a,
    const unsigned int* __restrict__ hist, double* __restrict__ ceb_a,
    unsigned int* __restrict__ cand_cnt, unsigned int* __restrict__ cand) {
  int s, rel, lo, hi;
  scale_of(blockIdx.x, s, rel, lo, hi);
  const int bid = blockIdx.x;
  if (s == 0)
    p2_main<HW0>(rel, 0, lo, hi, sc0, gl0, pcnt_a, ncnt_a, hist, ceb_a + bid,
                 cand_cnt, cand);
  else if (s == 1)
    p2_main<HW1>(rel, 1, lo, hi, sc1, gl1, pcnt_a, ncnt_a, hist, ceb_a + bid,
                 cand_cnt, cand);
  else
    p2_main<HW2>(rel, 2, lo, hi, sc2, gl2, pcnt_a, ncnt_a, hist, ceb_a + bid,
                 cand_cnt, cand);
}

// ------- pass 3: 3 blocks -- reduce + scan + radix select + finalize --------
__global__ __launch_bounds__(256) void k_select(
    const double* __restrict__ posce_a, const double* __restrict__ diff2_a,
    const double* __restrict__ ceb_a, const unsigned int* __restrict__ pcnt_a,
    const unsigned int* __restrict__ ncnt_a,
    const unsigned int* __restrict__ hist,
    const unsigned int* __restrict__ cand_cnt,
    const unsigned int* __restrict__ cand, float* __restrict__ out) {
  const int s = blockIdx.x;
  const int tid = threadIdx.x;
  const int lo = (s == 0) ? 0 : (s == 1) ? B0 : B0 + B1;
  const int hi = (s == 0) ? B0 : (s == 1) ? B0 + B1 : NBLK;

  __shared__ double sda[256], sdb[256], sdc[256];
  __shared__ unsigned int sua[256], sub[256];
  {
    double a = 0.0, b2 = 0.0, e = 0.0;
    unsigned int c = 0, d = 0;
    for (int i = lo + tid; i < hi; i += 256) {
      a += posce_a[i]; b2 += diff2_a[i]; e += ceb_a[i];
      c += pcnt_a[i];  d += ncnt_a[i];
    }
    sda[tid] = a; sdb[tid] = b2; sdc[tid] = e; sua[tid] = c; sub[tid] = d;
  }
  __syncthreads();
  for (int o = 128; o > 0; o >>= 1) {
    if (tid < o) {
      sda[tid] += sda[tid + o]; sdb[tid] += sdb[tid + o];
      sdc[tid] += sdc[tid + o];
      sua[tid] += sua[tid + o]; sub[tid] += sub[tid + o];
    }
    __syncthreads();
  }
  __shared__ double sh_posce, sh_diff2, sh_ceb;
  __shared__ unsigned int sh_pcnt, sh_k;
  if (tid == 0) {
    sh_posce = sda[0];
    sh_diff2 = sdb[0];
    sh_ceb = sdc[0];
    sh_pcnt = sua[0];
    const unsigned long long k10 = 10ull * (unsigned long long)sua[0];
    sh_k = (k10 < (unsigned long long)sub[0]) ? (unsigned int)k10 : sub[0];
  }
  __syncthreads();

  // count-only 256-bin scan -> selb, selr
  __shared__ unsigned int partC[256];
  __shared__ unsigned int sh_selb, sh_selr;
  const unsigned int ownC = hist[s * LBINS + tid];
  partC[tid] = ownC;
  __syncthreads();
  for (int o = 1; o < 256; o <<= 1) {
    const unsigned int aC = (tid >= o) ? partC[tid - o] : 0u;
    __syncthreads();
    partC[tid] += aC;
    __syncthreads();
  }
  {
    const unsigned int k = sh_k;
    const unsigned int inclC = partC[tid];
    const unsigned int exclC = inclC - ownC;
    if (ownC && k >= exclC && k < inclC) {
      sh_selb = (unsigned int)tid;
      sh_selr = k - exclC;
    }
  }
  __syncthreads();

  // exact radix select over candidates
  const unsigned int n = min(cand_cnt[s], (unsigned int)CAP);
  const unsigned int* lst = cand + s * CAP;
  __shared__ unsigned int dh[256];
  __shared__ unsigned int shp, shr, sh_w8, sh_nr;
  if (tid == 0) {
    shr = sh_selr;
    // bins >=1 span one binade -> candidates share bits 31:24
    shp = (sh_selb >= 1u) ? (lst[0] & 0xFF000000u) : 0u;
  }
  __syncthreads();
  const int r0 = (sh_selb >= 1u) ? 1 : 0;
  for (int round = r0; round < 4; ++round) {
    const int shift = 24 - 8 * round;
    dh[tid] = 0u;
    __syncthreads();
    const unsigned int pref = shp;
    for (unsigned int i = tid; i < n; i += 256) {
      const unsigned int v = lst[i];
      const bool match =
          (round == 0) || ((v >> (shift + 8)) == (pref >> (shift + 8)));
      if (match) atomicAdd(&dh[(v >> shift) & 255u], 1u);
    }
    __syncthreads();
    const unsigned int own = dh[tid];
    for (int o = 1; o < 256; o <<= 1) {  // inclusive scan in place
      const unsigned int add = (tid >= o) ? dh[tid - o] : 0u;
      __syncthreads();
      dh[tid] += add;
      __syncthreads();
    }
    const unsigned int incl = dh[tid];
    const unsigned int excl = incl - own;
    const unsigned int k = shr;
    if (own && k >= excl && k < incl) {
      sh_w8 = (unsigned int)tid;
      sh_nr = k - excl;
    }
    __syncthreads();
    if (tid == 0) {
      shp = pref | (sh_w8 << shift);
      shr = sh_nr;
    }
    __syncthreads();
  }
  const float thr = __uint_as_float(shp);

  // in-bin CE: candidates with 0 < v <= thr
  double acc = 0.0;
  for (unsigned int i = tid; i < n; i += 256) {
    const float v = __uint_as_float(lst[i]);
    if (v > 0.0f && v <= thr) acc += (double)(-__logf(v));
  }
  sda[tid] = acc;
  __syncthreads();
  for (int o = 128; o > 0; o >>= 1) {
    if (tid < o) sda[tid] += sda[tid + o];
    __syncthreads();
  }
  if (tid == 0) {
    const double Ns = (s == 0) ? (double)N0 : (s == 1) ? (double)N1 : (double)N2;
    const double W = (s == 0) ? 160.0 : (s == 1) ? 80.0 : 40.0;
    const double ls = (sh_posce + sh_ceb + sda[0]) / (2.0 * Ns);
    const double lb = (sh_diff2 / W) / (4.0 * (double)sh_pcnt);
    out[s] = (float)(ls + lb);
  }
}

extern "C" void kernel_launch(void* const* d_in, const int* in_sizes, int n_in,
                              void* d_out, int out_size, void* d_ws,
                              size_t ws_size, hipStream_t stream) {
  const float* sc0 = (const float*)d_in[0];
  const float* bb0 = (const float*)d_in[1];
  const float* gl0 = (const float*)d_in[3];
  const float* sc1 = (const float*)d_in[4];
  const float* bb1 = (const float*)d_in[5];
  const float* gl1 = (const float*)d_in[7];
  const float* sc2 = (const float*)d_in[8];
  const float* bb2 = (const float*)d_in[9];
  const float* gl2 = (const float*)d_in[11];

  char* ws = (char*)d_ws;
  unsigned int* hist = (unsigned int*)ws;              // 3*256 u32
  unsigned int* cand_cnt = hist + 3 * LBINS;           // 4 u32
  size_t zbytes = (size_t)3 * LBINS * 4 + 16;          // zeroed region
  zbytes = (zbytes + 255) & ~(size_t)255;
  size_t off = zbytes;
  double* posce_a = (double*)(ws + off);  off += (size_t)NBLK * 8;
  double* diff2_a = (double*)(ws + off);  off += (size_t)NBLK * 8;
  double* ceb_a = (double*)(ws + off);    off += (size_t)NBLK * 8;
  unsigned int* pcnt_a = (unsigned int*)(ws + off);  off += (size_t)NBLK * 4;
  unsigned int* ncnt_a = (unsigned int*)(ws + off);  off += (size_t)NBLK * 4;
  off = (off + 255) & ~(size_t)255;
  unsigned int* cand = (unsigned int*)(ws + off);      // 3*CAP u32

  const dim3 blk(256);
  k_zero<<<dim3(1), blk, 0, stream>>>((uint4*)d_ws, (int)(zbytes >> 4));
  k_pass1<<<dim3(NBLK), blk, 0, stream>>>(sc0, bb0, gl0, sc1, bb1, gl1, sc2,
                                          bb2, gl2, hist, posce_a, diff2_a,
                                          pcnt_a, ncnt_a);
  k_cand<<<dim3(NBLK), blk, 0, stream>>>(sc0, gl0, sc1, gl1, sc2, gl2, pcnt_a,
                                         ncnt_a, hist, ceb_a, cand_cnt, cand);
  k_select<<<dim3(3), blk, 0, stream>>>(posce_a, diff2_a, ceb_a, pcnt_a,
                                        ncnt_a, hist, cand_cnt, cand,
                                        (float*)d_out);
}

// Round 16
// 50.109 us; speedup vs baseline: 1.2967x; 1.0133x over previous
//
#include <hip/hip_runtime.h>

// ---------------------------------------------------------------------------
// cross_entropy_with_hnm_for_one_class_detection
//
// 3 scales: softmax-CE with hard-negative mining (k-th order statistic of
// neg_prob over N=B*H*W) + masked bbox MSE. Output: 3 floats.
//
// Proven skeleton (R13/R15, 50.8us): 525 blocks x 8 elem/thread, count-only
// 256-bin hist in pass1, k_cand recomputes v bitwise-identically
// (recompute > round-trip), no fences, 4 launches.
// R16 shaves:
//  - pass1 emits a pos-BITMASK (1 byte/thread, 134 KB) -> k_cand drops its
//    l0 stream entirely (-4.3 MB).
//  - neg_cnt == N_s - pos_cnt exactly (gt_label[:,1] = 1-gt_label[:,0])
//    -> ncnt array and its reductions removed.
// ---------------------------------------------------------------------------

namespace {
constexpr int HW0 = 25600, HW1 = 6400, HW2 = 1600;
constexpr int N0 = 32 * HW0;  // 819200
constexpr int N1 = 32 * HW1;  // 204800
constexpr int N2 = 32 * HW2;  // 51200

constexpr int LBINS = 256;
constexpr int CAP = 8192;  // candidate capacity per scale

// 2048 elements per block (two float4-quads per thread)
constexpr int B0 = N0 / 2048, B1 = N1 / 2048, B2 = N2 / 2048;  // 400,100,25
constexpr int NBLK = B0 + B1 + B2;                             // 525

__device__ __forceinline__ void scale_of(int bid, int& s, int& rel, int& lo,
                                         int& hi) {
  if (bid < B0) {
    s = 0; rel = bid; lo = 0; hi = B0;
  } else if (bid < B0 + B1) {
    s = 1; rel = bid - B0; lo = B0; hi = B0 + B1;
  } else {
    s = 2; rel = bid - B0 - B1; lo = B0 + B1; hi = NBLK;
  }
}

__device__ __forceinline__ unsigned int lin_bin(float v) {
  unsigned int b = (unsigned int)(v * 256.0f);
  return b > 255u ? 255u : b;
}
}  // namespace

// ---------------- pass 0: zero control region (~3.3 KB) ---------------------
__global__ __launch_bounds__(256) void k_zero(uint4* __restrict__ p, int n4) {
  for (int i = threadIdx.x; i < n4; i += 256) p[i] = make_uint4(0u, 0u, 0u, 0u);
}

// ------- pass 1: softmax stats, counts, pos-CE, bbox, hist + pos bitmask ----
template <int HW>
__device__ void p1_main(int rel, const float* __restrict__ sc,
                        const float* __restrict__ bb,
                        const float* __restrict__ gl,
                        unsigned int* __restrict__ histS,
                        double* __restrict__ posce_o,
                        double* __restrict__ diff2_o,
                        unsigned int* __restrict__ pcnt_o,
                        unsigned char* __restrict__ pmask_o) {
  __shared__ unsigned int lh[4][LBINS];  // wave-private count hists, 4 KiB
  const int tid = threadIdx.x, wid = tid >> 6;
#pragma unroll
  for (int w = 0; w < 4; ++w) lh[w][tid] = 0u;
  __syncthreads();

  // two quad-groups; all coalesced loads issued before any math
  const int q0 = (rel * 512 + tid) * 4;
  const int q1 = q0 + 1024;
  const int bA = q0 / HW, hwA = q0 - bA * HW;
  const int bB = q1 / HW, hwB = q1 - bB * HW;
  const float* scA = sc + (size_t)bA * 2 * HW + hwA;
  const float* scB = sc + (size_t)bB * 2 * HW + hwB;
  const float* glA = gl + (size_t)bA * 6 * HW + hwA;
  const float* glB = gl + (size_t)bB * 6 * HW + hwB;
  const float4 s0A = *(const float4*)scA;
  const float4 s1A = *(const float4*)(scA + HW);
  const float4 l0A = *(const float4*)glA;  // pos flag; neg = !pos
  const float4 s0B = *(const float4*)scB;
  const float4 s1B = *(const float4*)(scB + HW);
  const float4 l0B = *(const float4*)glB;

  double posce = 0.0, diff2 = 0.0;
  unsigned int pcnt = 0;
  unsigned int pbits = 0u;

  auto process = [&](const float4& s0v, const float4& s1v, const float4& l0v,
                     const float* __restrict__ glq,
                     const float* __restrict__ bbq, int bitbase) {
    const float s0a[4] = {s0v.x, s0v.y, s0v.z, s0v.w};
    const float s1a[4] = {s1v.x, s1v.y, s1v.z, s1v.w};
    const float l0a[4] = {l0v.x, l0v.y, l0v.z, l0v.w};
#pragma unroll
    for (int j = 0; j < 4; ++j) {
      const float d = s1a[j] - s0a[j];
      const float t = __expf(-fabsf(d));
      const float l1p = __logf(1.0f + t);  // lse after max-sub
      const bool pos = l0a[j] > 0.5f;
      const float sm1 = ((d >= 0.0f) ? 1.0f : t) / (1.0f + t);
      const float v = pos ? 0.0f : sm1;
      atomicAdd(&lh[wid][lin_bin(v)], 1u);
      if (pos) {
        pbits |= (1u << (bitbase + j));
        pcnt++;
        posce += (double)(l1p + ((d > 0.0f) ? d : 0.0f));  // = -ls0
        float acc = 0.0f;
#pragma unroll
        for (int c = 0; c < 4; ++c) {
          const float dd = glq[(2 + c) * HW + j] - bbq[c * HW + j];
          acc += dd * dd;
        }
        diff2 += (double)acc;
      }
    }
  };
  process(s0A, s1A, l0A, glA, bb + (size_t)bA * 4 * HW + hwA, 0);
  process(s0B, s1B, l0B, glB, bb + (size_t)bB * 4 * HW + hwB, 4);

  pmask_o[tid] = (unsigned char)pbits;

  __syncthreads();
  {  // flush counts: one bin per thread
    const unsigned int c = lh[0][tid] + lh[1][tid] + lh[2][tid] + lh[3][tid];
    if (c) atomicAdd(&histS[tid], c);
  }

  // reduce partials -> per-block SoA slots (no global atomics)
  for (int o = 32; o > 0; o >>= 1) {
    posce += __shfl_down(posce, o, 64);
    diff2 += __shfl_down(diff2, o, 64);
    pcnt += __shfl_down(pcnt, o, 64);
  }
  __shared__ double wa[4], wb[4];
  __shared__ unsigned int wc[4];
  if ((tid & 63) == 0) { wa[wid] = posce; wb[wid] = diff2; wc[wid] = pcnt; }
  __syncthreads();
  if (tid == 0) {
    *posce_o = wa[0] + wa[1] + wa[2] + wa[3];
    *diff2_o = wb[0] + wb[1] + wb[2] + wb[3];
    *pcnt_o = wc[0] + wc[1] + wc[2] + wc[3];
  }
}

__global__ __launch_bounds__(256) void k_pass1(
    const float* sc0, const float* bb0, const float* gl0,
    const float* sc1, const float* bb1, const float* gl1,
    const float* sc2, const float* bb2, const float* gl2,
    unsigned int* hist, double* posce_a, double* diff2_a,
    unsigned int* pcnt_a, unsigned char* pmask) {
  int s, rel, lo, hi;
  scale_of(blockIdx.x, s, rel, lo, hi);
  const int bid = blockIdx.x;
  unsigned char* pm = pmask + (size_t)bid * 256;
  if (s == 0)
    p1_main<HW0>(rel, sc0, bb0, gl0, hist, posce_a + bid, diff2_a + bid,
                 pcnt_a + bid, pm);
  else if (s == 1)
    p1_main<HW1>(rel, sc1, bb1, gl1, hist + LBINS, posce_a + bid,
                 diff2_a + bid, pcnt_a + bid, pm);
  else
    p1_main<HW2>(rel, sc2, bb2, gl2, hist + 2 * LBINS, posce_a + bid,
                 diff2_a + bid, pcnt_a + bid, pm);
}

// --- pass 2: recompute v; ce-below partial; gather in-bin candidates --------
template <int HW, int NS>
__device__ void p2_main(int rel, int s, int lo, int hi,
                        const float* __restrict__ sc,
                        const unsigned int* __restrict__ pcnt_a,
                        const unsigned char* __restrict__ pmask,
                        const unsigned int* __restrict__ hist,
                        double* __restrict__ ceb_o,
                        unsigned int* __restrict__ cand_cnt,
                        unsigned int* __restrict__ cand) {
  const int tid = threadIdx.x;

  // issue the bulk loads first; they stay in flight across the scan
  const int q0 = (rel * 512 + tid) * 4;
  const int q1 = q0 + 1024;
  const int bA = q0 / HW, hwA = q0 - bA * HW;
  const int bB = q1 / HW, hwB = q1 - bB * HW;
  const float* scA = sc + (size_t)bA * 2 * HW + hwA;
  const float* scB = sc + (size_t)bB * 2 * HW + hwB;
  const float4 s0A = *(const float4*)scA;
  const float4 s1A = *(const float4*)(scA + HW);
  const float4 s0B = *(const float4*)scB;
  const float4 s1B = *(const float4*)(scB + HW);
  const unsigned int pbits = pmask[tid];  // 8 pos bits for this thread

  // redundant pos-count reduce (L2-hot, ~2 KB)
  __shared__ unsigned int sua[256];
  {
    unsigned int c = 0;
    for (int i = lo + tid; i < hi; i += 256) c += pcnt_a[i];
    sua[tid] = c;
  }
  __syncthreads();
  for (int o = 128; o > 0; o >>= 1) {
    if (tid < o) sua[tid] += sua[tid + o];
    __syncthreads();
  }
  __shared__ unsigned int sh_k;
  if (tid == 0) {
    const unsigned int pos = sua[0];
    const unsigned int neg = (unsigned int)NS - pos;
    const unsigned long long k10 = 10ull * (unsigned long long)pos;
    sh_k = (k10 < (unsigned long long)neg) ? (unsigned int)k10 : neg;
  }
  __syncthreads();

  // count-only 256-bin scan -> sel_bin
  __shared__ unsigned int partC[256];
  __shared__ unsigned int sh_selb;
  const unsigned int ownC = hist[s * LBINS + tid];
  partC[tid] = ownC;
  __syncthreads();
  for (int o = 1; o < 256; o <<= 1) {
    const unsigned int aC = (tid >= o) ? partC[tid - o] : 0u;
    __syncthreads();
    partC[tid] += aC;
    __syncthreads();
  }
  {
    const unsigned int k = sh_k;
    const unsigned int inclC = partC[tid];
    const unsigned int exclC = inclC - ownC;
    if (ownC && k >= exclC && k < inclC) sh_selb = (unsigned int)tid;
  }
  __syncthreads();

  // recompute v (bitwise == pass1), sum ce for bins < selb, gather in-bin
  __shared__ unsigned int cbuf[512];
  __shared__ unsigned int ccnt, cbase;
  if (tid == 0) ccnt = 0u;
  __syncthreads();
  const unsigned int bsel = sh_selb;
  double ceb = 0.0;

  auto scan8 = [&](const float4& s0v, const float4& s1v, int bitbase) {
    const float s0a[4] = {s0v.x, s0v.y, s0v.z, s0v.w};
    const float s1a[4] = {s1v.x, s1v.y, s1v.z, s1v.w};
#pragma unroll
    for (int j = 0; j < 4; ++j) {
      if (pbits & (1u << (bitbase + j))) continue;  // pos: no neg-CE
      const float d = s1a[j] - s0a[j];
      const float t = __expf(-fabsf(d));
      const float v = ((d >= 0.0f) ? 1.0f : t) / (1.0f + t);
      const unsigned int bin = lin_bin(v);
      if (bin < bsel) {
        ceb += (double)(__logf(1.0f + t) + ((d >= 0.0f) ? 0.0f : -d));
      } else if (bin == bsel) {
        const unsigned int sl = atomicAdd(&ccnt, 1u);
        if (sl < 512u) {
          cbuf[sl] = __float_as_uint(v);
        } else {  // overflow fallback (rare)
          const unsigned int g2 = atomicAdd(&cand_cnt[s], 1u);
          if (g2 < (unsigned)CAP) cand[s * CAP + g2] = __float_as_uint(v);
        }
      }
    }
  };
  scan8(s0A, s1A, 0);
  scan8(s0B, s1B, 4);
  __syncthreads();
  if (tid == 0) {
    const unsigned int n = min(ccnt, 512u);
    cbase = n ? atomicAdd(&cand_cnt[s], n) : 0u;
  }
  __syncthreads();
  {
    const unsigned int n = min(ccnt, 512u);
    for (unsigned int i = tid; i < n; i += 256) {
      const unsigned int idx = cbase + i;
      if (idx < (unsigned)CAP) cand[s * CAP + idx] = cbuf[i];
    }
  }

  // reduce ceb -> per-block slot
  for (int o = 32; o > 0; o >>= 1) ceb += __shfl_down(ceb, o, 64);
  __shared__ double wv[4];
  if ((tid & 63) == 0) wv[tid >> 6] = ceb;
  __syncthreads();
  if (tid == 0) *ceb_o = wv[0] + wv[1] + wv[2] + wv[3];
}

__global__ __launch_bounds__(256) void k_cand(
    const float* sc0, const float* sc1, const float* sc2,
    const unsigned int* __restrict__ pcnt_a,
    const unsigned char* __restrict__ pmask,
    const unsigned int* __restrict__ hist, double* __restrict__ ceb_a,
    unsigned int* __restrict__ cand_cnt, unsigned int* __restrict__ cand) {
  int s, rel, lo, hi;
  scale_of(blockIdx.x, s, rel, lo, hi);
  const int bid = blockIdx.x;
  const unsigned char* pm = pmask + (size_t)bid * 256;
  if (s == 0)
    p2_main<HW0, N0>(rel, 0, lo, hi, sc0, pcnt_a, pm, hist, ceb_a + bid,
                     cand_cnt, cand);
  else if (s == 1)
    p2_main<HW1, N1>(rel, 1, lo, hi, sc1, pcnt_a, pm, hist, ceb_a + bid,
                     cand_cnt, cand);
  else
    p2_main<HW2, N2>(rel, 2, lo, hi, sc2, pcnt_a, pm, hist, ceb_a + bid,
                     cand_cnt, cand);
}

// ------- pass 3: 3 blocks -- reduce + scan + radix select + finalize --------
__global__ __launch_bounds__(256) void k_select(
    const double* __restrict__ posce_a, const double* __restrict__ diff2_a,
    const double* __restrict__ ceb_a, const unsigned int* __restrict__ pcnt_a,
    const unsigned int* __restrict__ hist,
    const unsigned int* __restrict__ cand_cnt,
    const unsigned int* __restrict__ cand, float* __restrict__ out) {
  const int s = blockIdx.x;
  const int tid = threadIdx.x;
  const int lo = (s == 0) ? 0 : (s == 1) ? B0 : B0 + B1;
  const int hi = (s == 0) ? B0 : (s == 1) ? B0 + B1 : NBLK;
  const unsigned int NS =
      (s == 0) ? (unsigned)N0 : (s == 1) ? (unsigned)N1 : (unsigned)N2;

  __shared__ double sda[256], sdb[256], sdc[256];
  __shared__ unsigned int sua[256];
  {
    double a = 0.0, b2 = 0.0, e = 0.0;
    unsigned int c = 0;
    for (int i = lo + tid; i < hi; i += 256) {
      a += posce_a[i]; b2 += diff2_a[i]; e += ceb_a[i];
      c += pcnt_a[i];
    }
    sda[tid] = a; sdb[tid] = b2; sdc[tid] = e; sua[tid] = c;
  }
  __syncthreads();
  for (int o = 128; o > 0; o >>= 1) {
    if (tid < o) {
      sda[tid] += sda[tid + o]; sdb[tid] += sdb[tid + o];
      sdc[tid] += sdc[tid + o]; sua[tid] += sua[tid + o];
    }
    __syncthreads();
  }
  __shared__ double sh_posce, sh_diff2, sh_ceb;
  __shared__ unsigned int sh_pcnt, sh_k;
  if (tid == 0) {
    sh_posce = sda[0];
    sh_diff2 = sdb[0];
    sh_ceb = sdc[0];
    sh_pcnt = sua[0];
    const unsigned int neg = NS - sua[0];
    const unsigned long long k10 = 10ull * (unsigned long long)sua[0];
    sh_k = (k10 < (unsigned long long)neg) ? (unsigned int)k10 : neg;
  }
  __syncthreads();

  // count-only 256-bin scan -> selb, selr
  __shared__ unsigned int partC[256];
  __shared__ unsigned int sh_selb, sh_selr;
  const unsigned int ownC = hist[s * LBINS + tid];
  partC[tid] = ownC;
  __syncthreads();
  for (int o = 1; o < 256; o <<= 1) {
    const unsigned int aC = (tid >= o) ? partC[tid - o] : 0u;
    __syncthreads();
    partC[tid] += aC;
    __syncthreads();
  }
  {
    const unsigned int k = sh_k;
    const unsigned int inclC = partC[tid];
    const unsigned int exclC = inclC - ownC;
    if (ownC && k >= exclC && k < inclC) {
      sh_selb = (unsigned int)tid;
      sh_selr = k - exclC;
    }
  }
  __syncthreads();

  // exact radix select over candidates
  const unsigned int n = min(cand_cnt[s], (unsigned int)CAP);
  const unsigned int* lst = cand + s * CAP;
  __shared__ unsigned int dh[256];
  __shared__ unsigned int shp, shr, sh_w8, sh_nr;
  if (tid == 0) {
    shr = sh_selr;
    // bins >=1 lie within one binade -> candidates share bits 31:24
    shp = (sh_selb >= 1u) ? (lst[0] & 0xFF000000u) : 0u;
  }
  __syncthreads();
  const int r0 = (sh_selb >= 1u) ? 1 : 0;
  for (int round = r0; round < 4; ++round) {
    const int shift = 24 - 8 * round;
    dh[tid] = 0u;
    __syncthreads();
    const unsigned int pref = shp;
    for (unsigned int i = tid; i < n; i += 256) {
      const unsigned int v = lst[i];
      const bool match =
          (round == 0) || ((v >> (shift + 8)) == (pref >> (shift + 8)));
      if (match) atomicAdd(&dh[(v >> shift) & 255u], 1u);
    }
    __syncthreads();
    const unsigned int own = dh[tid];
    for (int o = 1; o < 256; o <<= 1) {  // inclusive scan in place
      const unsigned int add = (tid >= o) ? dh[tid - o] : 0u;
      __syncthreads();
      dh[tid] += add;
      __syncthreads();
    }
    const unsigned int incl = dh[tid];
    const unsigned int excl = incl - own;
    const unsigned int k = shr;
    if (own && k >= excl && k < incl) {
      sh_w8 = (unsigned int)tid;
      sh_nr = k - excl;
    }
    __syncthreads();
    if (tid == 0) {
      shp = pref | (sh_w8 << shift);
      shr = sh_nr;
    }
    __syncthreads();
  }
  const float thr = __uint_as_float(shp);

  // in-bin CE: candidates with 0 < v <= thr
  double acc = 0.0;
  for (unsigned int i = tid; i < n; i += 256) {
    const float v = __uint_as_float(lst[i]);
    if (v > 0.0f && v <= thr) acc += (double)(-__logf(v));
  }
  sda[tid] = acc;
  __syncthreads();
  for (int o = 128; o > 0; o >>= 1) {
    if (tid < o) sda[tid] += sda[tid + o];
    __syncthreads();
  }
  if (tid == 0) {
    const double Ns = (double)NS;
    const double W = (s == 0) ? 160.0 : (s == 1) ? 80.0 : 40.0;
    const double ls = (sh_posce + sh_ceb + sda[0]) / (2.0 * Ns);
    const double lb = (sh_diff2 / W) / (4.0 * (double)sh_pcnt);
    out[s] = (float)(ls + lb);
  }
}

extern "C" void kernel_launch(void* const* d_in, const int* in_sizes, int n_in,
                              void* d_out, int out_size, void* d_ws,
                              size_t ws_size, hipStream_t stream) {
  const float* sc0 = (const float*)d_in[0];
  const float* bb0 = (const float*)d_in[1];
  const float* gl0 = (const float*)d_in[3];
  const float* sc1 = (const float*)d_in[4];
  const float* bb1 = (const float*)d_in[5];
  const float* gl1 = (const float*)d_in[7];
  const float* sc2 = (const float*)d_in[8];
  const float* bb2 = (const float*)d_in[9];
  const float* gl2 = (const float*)d_in[11];

  char* ws = (char*)d_ws;
  unsigned int* hist = (unsigned int*)ws;              // 3*256 u32
  unsigned int* cand_cnt = hist + 3 * LBINS;           // 4 u32
  size_t zbytes = (size_t)3 * LBINS * 4 + 16;          // zeroed region
  zbytes = (zbytes + 255) & ~(size_t)255;
  size_t off = zbytes;
  double* posce_a = (double*)(ws + off);  off += (size_t)NBLK * 8;
  double* diff2_a = (double*)(ws + off);  off += (size_t)NBLK * 8;
  double* ceb_a = (double*)(ws + off);    off += (size_t)NBLK * 8;
  unsigned int* pcnt_a = (unsigned int*)(ws + off);  off += (size_t)NBLK * 4;
  off = (off + 255) & ~(size_t)255;
  unsigned char* pmask = (unsigned char*)(ws + off);   // NBLK*256 u8
  off += (size_t)NBLK * 256;
  off = (off + 255) & ~(size_t)255;
  unsigned int* cand = (unsigned int*)(ws + off);      // 3*CAP u32

  const dim3 blk(256);
  k_zero<<<dim3(1), blk, 0, stream>>>((uint4*)d_ws, (int)(zbytes >> 4));
  k_pass1<<<dim3(NBLK), blk, 0, stream>>>(sc0, bb0, gl0, sc1, bb1, gl1, sc2,
                                          bb2, gl2, hist, posce_a, diff2_a,
                                          pcnt_a, pmask);
  k_cand<<<dim3(NBLK), blk, 0, stream>>>(sc0, sc1, sc2, pcnt_a, pmask, hist,
                                         ceb_a, cand_cnt, cand);
  k_select<<<dim3(3), blk, 0, stream>>>(posce_a, diff2_a, ceb_a, pcnt_a, hist,
                                        cand_cnt, cand, (float*)d_out);
}

// Round 17
// 49.642 us; speedup vs baseline: 1.3089x; 1.0094x over previous
//
#include <hip/hip_runtime.h>

// ---------------------------------------------------------------------------
// cross_entropy_with_hnm_for_one_class_detection
//
// 3 scales: softmax-CE with hard-negative mining (k-th order statistic of
// neg_prob over N=B*H*W) + masked bbox MSE. Output: 3 floats.
//
// R16 lesson: traffic shaves stopped paying -> latency-bound at 8 waves/CU
// (525 blocks x 256 thr = 2.05 blk/CU). R17 single knob: 512-thread blocks
// (same 525 blocks, same 2048 elem/block, same per-block overhead) ->
// 16 waves/CU, 2x loads in flight. Skeleton otherwise identical:
//   k_zero -> k_pass1 -> k_cand (recompute) -> k_select. No fences.
// ---------------------------------------------------------------------------

namespace {
constexpr int HW0 = 25600, HW1 = 6400, HW2 = 1600;
constexpr int N0 = 32 * HW0;  // 819200
constexpr int N1 = 32 * HW1;  // 204800
constexpr int N2 = 32 * HW2;  // 51200

constexpr int LBINS = 256;
constexpr int CAP = 8192;  // candidate capacity per scale

// 2048 elements per block (512 threads x 4 elem)
constexpr int B0 = N0 / 2048, B1 = N1 / 2048, B2 = N2 / 2048;  // 400,100,25
constexpr int NBLK = B0 + B1 + B2;                             // 525

__device__ __forceinline__ void scale_of(int bid, int& s, int& rel, int& lo,
                                         int& hi) {
  if (bid < B0) {
    s = 0; rel = bid; lo = 0; hi = B0;
  } else if (bid < B0 + B1) {
    s = 1; rel = bid - B0; lo = B0; hi = B0 + B1;
  } else {
    s = 2; rel = bid - B0 - B1; lo = B0 + B1; hi = NBLK;
  }
}

__device__ __forceinline__ unsigned int lin_bin(float v) {
  unsigned int b = (unsigned int)(v * 256.0f);
  return b > 255u ? 255u : b;
}
}  // namespace

// ---------------- pass 0: zero control region (~3.3 KB) ---------------------
__global__ __launch_bounds__(256) void k_zero(uint4* __restrict__ p, int n4) {
  for (int i = threadIdx.x; i < n4; i += 256) p[i] = make_uint4(0u, 0u, 0u, 0u);
}

// ------- pass 1: softmax stats, counts, pos-CE, bbox, hist + pos bitmask ----
template <int HW>
__device__ void p1_main(int rel, const float* __restrict__ sc,
                        const float* __restrict__ bb,
                        const float* __restrict__ gl,
                        unsigned int* __restrict__ histS,
                        double* __restrict__ posce_o,
                        double* __restrict__ diff2_o,
                        unsigned int* __restrict__ pcnt_o,
                        unsigned char* __restrict__ pmask_o) {
  __shared__ unsigned int lh[8][LBINS];  // wave-private count hists, 8 KiB
  const int tid = threadIdx.x, wid = tid >> 6;
  for (int i = tid; i < 8 * LBINS; i += 512) ((unsigned int*)lh)[i] = 0u;
  __syncthreads();

  // one quad per thread; all coalesced loads issued before any math
  const int q0 = (rel * 512 + tid) * 4;
  const int bA = q0 / HW, hwA = q0 - bA * HW;
  const float* scA = sc + (size_t)bA * 2 * HW + hwA;
  const float* glA = gl + (size_t)bA * 6 * HW + hwA;
  const float4 s0A = *(const float4*)scA;
  const float4 s1A = *(const float4*)(scA + HW);
  const float4 l0A = *(const float4*)glA;  // pos flag; neg = !pos

  double posce = 0.0, diff2 = 0.0;
  unsigned int pcnt = 0;
  unsigned int pbits = 0u;
  {
    const float* bbq = bb + (size_t)bA * 4 * HW + hwA;
    const float s0a[4] = {s0A.x, s0A.y, s0A.z, s0A.w};
    const float s1a[4] = {s1A.x, s1A.y, s1A.z, s1A.w};
    const float l0a[4] = {l0A.x, l0A.y, l0A.z, l0A.w};
#pragma unroll
    for (int j = 0; j < 4; ++j) {
      const float d = s1a[j] - s0a[j];
      const float t = __expf(-fabsf(d));
      const float l1p = __logf(1.0f + t);  // lse after max-sub
      const bool pos = l0a[j] > 0.5f;
      const float sm1 = ((d >= 0.0f) ? 1.0f : t) / (1.0f + t);
      const float v = pos ? 0.0f : sm1;
      atomicAdd(&lh[wid][lin_bin(v)], 1u);
      if (pos) {
        pbits |= (1u << j);
        pcnt++;
        posce += (double)(l1p + ((d > 0.0f) ? d : 0.0f));  // = -ls0
        float acc = 0.0f;
#pragma unroll
        for (int c = 0; c < 4; ++c) {
          const float dd = glA[(2 + c) * HW + j] - bbq[c * HW + j];
          acc += dd * dd;
        }
        diff2 += (double)acc;
      }
    }
  }
  pmask_o[tid] = (unsigned char)pbits;

  __syncthreads();
  if (tid < LBINS) {  // flush counts: one bin per thread
    unsigned int c = 0;
#pragma unroll
    for (int w = 0; w < 8; ++w) c += lh[w][tid];
    if (c) atomicAdd(&histS[tid], c);
  }

  // reduce partials -> per-block SoA slots (no global atomics)
  for (int o = 32; o > 0; o >>= 1) {
    posce += __shfl_down(posce, o, 64);
    diff2 += __shfl_down(diff2, o, 64);
    pcnt += __shfl_down(pcnt, o, 64);
  }
  __shared__ double wa[8], wb[8];
  __shared__ unsigned int wc[8];
  if ((tid & 63) == 0) { wa[wid] = posce; wb[wid] = diff2; wc[wid] = pcnt; }
  __syncthreads();
  if (tid == 0) {
    double a = 0.0, b2 = 0.0;
    unsigned int c = 0;
#pragma unroll
    for (int w = 0; w < 8; ++w) { a += wa[w]; b2 += wb[w]; c += wc[w]; }
    *posce_o = a;
    *diff2_o = b2;
    *pcnt_o = c;
  }
}

__global__ __launch_bounds__(512) void k_pass1(
    const float* sc0, const float* bb0, const float* gl0,
    const float* sc1, const float* bb1, const float* gl1,
    const float* sc2, const float* bb2, const float* gl2,
    unsigned int* hist, double* posce_a, double* diff2_a,
    unsigned int* pcnt_a, unsigned char* pmask) {
  int s, rel, lo, hi;
  scale_of(blockIdx.x, s, rel, lo, hi);
  const int bid = blockIdx.x;
  unsigned char* pm = pmask + (size_t)bid * 512;
  if (s == 0)
    p1_main<HW0>(rel, sc0, bb0, gl0, hist, posce_a + bid, diff2_a + bid,
                 pcnt_a + bid, pm);
  else if (s == 1)
    p1_main<HW1>(rel, sc1, bb1, gl1, hist + LBINS, posce_a + bid,
                 diff2_a + bid, pcnt_a + bid, pm);
  else
    p1_main<HW2>(rel, sc2, bb2, gl2, hist + 2 * LBINS, posce_a + bid,
                 diff2_a + bid, pcnt_a + bid, pm);
}

// --- pass 2: recompute v; ce-below partial; gather in-bin candidates --------
template <int HW, int NS>
__device__ void p2_main(int rel, int s, int lo, int hi,
                        const float* __restrict__ sc,
                        const unsigned int* __restrict__ pcnt_a,
                        const unsigned char* __restrict__ pmask,
                        const unsigned int* __restrict__ hist,
                        double* __restrict__ ceb_o,
                        unsigned int* __restrict__ cand_cnt,
                        unsigned int* __restrict__ cand) {
  const int tid = threadIdx.x, wid = tid >> 6;

  // issue the bulk loads first; they stay in flight across the scan
  const int q0 = (rel * 512 + tid) * 4;
  const int bA = q0 / HW, hwA = q0 - bA * HW;
  const float* scA = sc + (size_t)bA * 2 * HW + hwA;
  const float4 s0A = *(const float4*)scA;
  const float4 s1A = *(const float4*)(scA + HW);
  const unsigned int pbits = pmask[tid];  // 4 pos bits for this thread

  // redundant pos-count reduce (L2-hot, ~2 KB)
  __shared__ unsigned int sua[512];
  {
    unsigned int c = 0;
    for (int i = lo + tid; i < hi; i += 512) c += pcnt_a[i];
    sua[tid] = c;
  }
  __syncthreads();
  for (int o = 256; o > 0; o >>= 1) {
    if (tid < o) sua[tid] += sua[tid + o];
    __syncthreads();
  }
  __shared__ unsigned int sh_k;
  if (tid == 0) {
    const unsigned int pos = sua[0];
    const unsigned int neg = (unsigned int)NS - pos;
    const unsigned long long k10 = 10ull * (unsigned long long)pos;
    sh_k = (k10 < (unsigned long long)neg) ? (unsigned int)k10 : neg;
  }
  __syncthreads();

  // count-only 256-bin scan -> sel_bin (tid<256 active; all-thread barriers)
  __shared__ unsigned int partC[256];
  __shared__ unsigned int sh_selb;
  unsigned int ownC = 0;
  if (tid < LBINS) {
    ownC = hist[s * LBINS + tid];
    partC[tid] = ownC;
  }
  __syncthreads();
  for (int o = 1; o < 256; o <<= 1) {
    const unsigned int aC = (tid < LBINS && tid >= o) ? partC[tid - o] : 0u;
    __syncthreads();
    if (tid < LBINS) partC[tid] += aC;
    __syncthreads();
  }
  if (tid < LBINS) {
    const unsigned int k = sh_k;
    const unsigned int inclC = partC[tid];
    const unsigned int exclC = inclC - ownC;
    if (ownC && k >= exclC && k < inclC) sh_selb = (unsigned int)tid;
  }
  __syncthreads();

  // recompute v (bitwise == pass1), sum ce for bins < selb, gather in-bin
  __shared__ unsigned int cbuf[512];
  __shared__ unsigned int ccnt, cbase;
  if (tid == 0) ccnt = 0u;
  __syncthreads();
  const unsigned int bsel = sh_selb;
  double ceb = 0.0;
  {
    const float s0a[4] = {s0A.x, s0A.y, s0A.z, s0A.w};
    const float s1a[4] = {s1A.x, s1A.y, s1A.z, s1A.w};
#pragma unroll
    for (int j = 0; j < 4; ++j) {
      if (pbits & (1u << j)) continue;  // pos: no neg-CE
      const float d = s1a[j] - s0a[j];
      const float t = __expf(-fabsf(d));
      const float v = ((d >= 0.0f) ? 1.0f : t) / (1.0f + t);
      const unsigned int bin = lin_bin(v);
      if (bin < bsel) {
        ceb += (double)(__logf(1.0f + t) + ((d >= 0.0f) ? 0.0f : -d));
      } else if (bin == bsel) {
        const unsigned int sl = atomicAdd(&ccnt, 1u);
        if (sl < 512u) {
          cbuf[sl] = __float_as_uint(v);
        } else {  // overflow fallback (rare)
          const unsigned int g2 = atomicAdd(&cand_cnt[s], 1u);
          if (g2 < (unsigned)CAP) cand[s * CAP + g2] = __float_as_uint(v);
        }
      }
    }
  }
  __syncthreads();
  if (tid == 0) {
    const unsigned int n = min(ccnt, 512u);
    cbase = n ? atomicAdd(&cand_cnt[s], n) : 0u;
  }
  __syncthreads();
  {
    const unsigned int n = min(ccnt, 512u);
    for (unsigned int i = tid; i < n; i += 512) {
      const unsigned int idx = cbase + i;
      if (idx < (unsigned)CAP) cand[s * CAP + idx] = cbuf[i];
    }
  }

  // reduce ceb -> per-block slot
  for (int o = 32; o > 0; o >>= 1) ceb += __shfl_down(ceb, o, 64);
  __shared__ double wv[8];
  if ((tid & 63) == 0) wv[wid] = ceb;
  __syncthreads();
  if (tid == 0) {
    double e = 0.0;
#pragma unroll
    for (int w = 0; w < 8; ++w) e += wv[w];
    *ceb_o = e;
  }
}

__global__ __launch_bounds__(512) void k_cand(
    const float* sc0, const float* sc1, const float* sc2,
    const unsigned int* __restrict__ pcnt_a,
    const unsigned char* __restrict__ pmask,
    const unsigned int* __restrict__ hist, double* __restrict__ ceb_a,
    unsigned int* __restrict__ cand_cnt, unsigned int* __restrict__ cand) {
  int s, rel, lo, hi;
  scale_of(blockIdx.x, s, rel, lo, hi);
  const int bid = blockIdx.x;
  const unsigned char* pm = pmask + (size_t)bid * 512;
  if (s == 0)
    p2_main<HW0, N0>(rel, 0, lo, hi, sc0, pcnt_a, pm, hist, ceb_a + bid,
                     cand_cnt, cand);
  else if (s == 1)
    p2_main<HW1, N1>(rel, 1, lo, hi, sc1, pcnt_a, pm, hist, ceb_a + bid,
                     cand_cnt, cand);
  else
    p2_main<HW2, N2>(rel, 2, lo, hi, sc2, pcnt_a, pm, hist, ceb_a + bid,
                     cand_cnt, cand);
}

// ------- pass 3: 3 blocks -- reduce + scan + radix select + finalize --------
__global__ __launch_bounds__(256) void k_select(
    const double* __restrict__ posce_a, const double* __restrict__ diff2_a,
    const double* __restrict__ ceb_a, const unsigned int* __restrict__ pcnt_a,
    const unsigned int* __restrict__ hist,
    const unsigned int* __restrict__ cand_cnt,
    const unsigned int* __restrict__ cand, float* __restrict__ out) {
  const int s = blockIdx.x;
  const int tid = threadIdx.x;
  const int lo = (s == 0) ? 0 : (s == 1) ? B0 : B0 + B1;
  const int hi = (s == 0) ? B0 : (s == 1) ? B0 + B1 : NBLK;
  const unsigned int NS =
      (s == 0) ? (unsigned)N0 : (s == 1) ? (unsigned)N1 : (unsigned)N2;

  __shared__ double sda[256], sdb[256], sdc[256];
  __shared__ unsigned int sua[256];
  {
    double a = 0.0, b2 = 0.0, e = 0.0;
    unsigned int c = 0;
    for (int i = lo + tid; i < hi; i += 256) {
      a += posce_a[i]; b2 += diff2_a[i]; e += ceb_a[i];
      c += pcnt_a[i];
    }
    sda[tid] = a; sdb[tid] = b2; sdc[tid] = e; sua[tid] = c;
  }
  __syncthreads();
  for (int o = 128; o > 0; o >>= 1) {
    if (tid < o) {
      sda[tid] += sda[tid + o]; sdb[tid] += sdb[tid + o];
      sdc[tid] += sdc[tid + o]; sua[tid] += sua[tid + o];
    }
    __syncthreads();
  }
  __shared__ double sh_posce, sh_diff2, sh_ceb;
  __shared__ unsigned int sh_pcnt, sh_k;
  if (tid == 0) {
    sh_posce = sda[0];
    sh_diff2 = sdb[0];
    sh_ceb = sdc[0];
    sh_pcnt = sua[0];
    const unsigned int neg = NS - sua[0];
    const unsigned long long k10 = 10ull * (unsigned long long)sua[0];
    sh_k = (k10 < (unsigned long long)neg) ? (unsigned int)k10 : neg;
  }
  __syncthreads();

  // count-only 256-bin scan -> selb, selr
  __shared__ unsigned int partC[256];
  __shared__ unsigned int sh_selb, sh_selr;
  const unsigned int ownC = hist[s * LBINS + tid];
  partC[tid] = ownC;
  __syncthreads();
  for (int o = 1; o < 256; o <<= 1) {
    const unsigned int aC = (tid >= o) ? partC[tid - o] : 0u;
    __syncthreads();
    partC[tid] += aC;
    __syncthreads();
  }
  {
    const unsigned int k = sh_k;
    const unsigned int inclC = partC[tid];
    const unsigned int exclC = inclC - ownC;
    if (ownC && k >= exclC && k < inclC) {
      sh_selb = (unsigned int)tid;
      sh_selr = k - exclC;
    }
  }
  __syncthreads();

  // exact radix select over candidates
  const unsigned int n = min(cand_cnt[s], (unsigned int)CAP);
  const unsigned int* lst = cand + s * CAP;
  __shared__ unsigned int dh[256];
  __shared__ unsigned int shp, shr, sh_w8, sh_nr;
  if (tid == 0) {
    shr = sh_selr;
    // bins >=1 lie within one binade -> candidates share bits 31:24
    shp = (sh_selb >= 1u) ? (lst[0] & 0xFF000000u) : 0u;
  }
  __syncthreads();
  const int r0 = (sh_selb >= 1u) ? 1 : 0;
  for (int round = r0; round < 4; ++round) {
    const int shift = 24 - 8 * round;
    dh[tid] = 0u;
    __syncthreads();
    const unsigned int pref = shp;
    for (unsigned int i = tid; i < n; i += 256) {
      const unsigned int v = lst[i];
      const bool match =
          (round == 0) || ((v >> (shift + 8)) == (pref >> (shift + 8)));
      if (match) atomicAdd(&dh[(v >> shift) & 255u], 1u);
    }
    __syncthreads();
    const unsigned int own = dh[tid];
    for (int o = 1; o < 256; o <<= 1) {  // inclusive scan in place
      const unsigned int add = (tid >= o) ? dh[tid - o] : 0u;
      __syncthreads();
      dh[tid] += add;
      __syncthreads();
    }
    const unsigned int incl = dh[tid];
    const unsigned int excl = incl - own;
    const unsigned int k = shr;
    if (own && k >= excl && k < incl) {
      sh_w8 = (unsigned int)tid;
      sh_nr = k - excl;
    }
    __syncthreads();
    if (tid == 0) {
      shp = pref | (sh_w8 << shift);
      shr = sh_nr;
    }
    __syncthreads();
  }
  const float thr = __uint_as_float(shp);

  // in-bin CE: candidates with 0 < v <= thr
  double acc = 0.0;
  for (unsigned int i = tid; i < n; i += 256) {
    const float v = __uint_as_float(lst[i]);
    if (v > 0.0f && v <= thr) acc += (double)(-__logf(v));
  }
  sda[tid] = acc;
  __syncthreads();
  for (int o = 128; o > 0; o >>= 1) {
    if (tid < o) sda[tid] += sda[tid + o];
    __syncthreads();
  }
  if (tid == 0) {
    const double Ns = (double)NS;
    const double W = (s == 0) ? 160.0 : (s == 1) ? 80.0 : 40.0;
    const double ls = (sh_posce + sh_ceb + sda[0]) / (2.0 * Ns);
    const double lb = (sh_diff2 / W) / (4.0 * (double)sh_pcnt);
    out[s] = (float)(ls + lb);
  }
}

extern "C" void kernel_launch(void* const* d_in, const int* in_sizes, int n_in,
                              void* d_out, int out_size, void* d_ws,
                              size_t ws_size, hipStream_t stream) {
  const float* sc0 = (const float*)d_in[0];
  const float* bb0 = (const float*)d_in[1];
  const float* gl0 = (const float*)d_in[3];
  const float* sc1 = (const float*)d_in[4];
  const float* bb1 = (const float*)d_in[5];
  const float* gl1 = (const float*)d_in[7];
  const float* sc2 = (const float*)d_in[8];
  const float* bb2 = (const float*)d_in[9];
  const float* gl2 = (const float*)d_in[11];

  char* ws = (char*)d_ws;
  unsigned int* hist = (unsigned int*)ws;              // 3*256 u32
  unsigned int* cand_cnt = hist + 3 * LBINS;           // 4 u32
  size_t zbytes = (size_t)3 * LBINS * 4 + 16;          // zeroed region
  zbytes = (zbytes + 255) & ~(size_t)255;
  size_t off = zbytes;
  double* posce_a = (double*)(ws + off);  off += (size_t)NBLK * 8;
  double* diff2_a = (double*)(ws + off);  off += (size_t)NBLK * 8;
  double* ceb_a = (double*)(ws + off);    off += (size_t)NBLK * 8;
  unsigned int* pcnt_a = (unsigned int*)(ws + off);  off += (size_t)NBLK * 4;
  off = (off + 255) & ~(size_t)255;
  unsigned char* pmask = (unsigned char*)(ws + off);   // NBLK*512 u8
  off += (size_t)NBLK * 512;
  off = (off + 255) & ~(size_t)255;
  unsigned int* cand = (unsigned int*)(ws + off);      // 3*CAP u32

  k_zero<<<dim3(1), dim3(256), 0, stream>>>((uint4*)d_ws, (int)(zbytes >> 4));
  k_pass1<<<dim3(NBLK), dim3(512), 0, stream>>>(sc0, bb0, gl0, sc1, bb1, gl1,
                                                sc2, bb2, gl2, hist, posce_a,
                                                diff2_a, pcnt_a, pmask);
  k_cand<<<dim3(NBLK), dim3(512), 0, stream>>>(sc0, sc1, sc2, pcnt_a, pmask,
                                               hist, ceb_a, cand_cnt, cand);
  k_select<<<dim3(3), dim3(256), 0, stream>>>(posce_a, diff2_a, ceb_a, pcnt_a,
                                              hist, cand_cnt, cand,
                                              (float*)d_out);
}

// Round 18
// 48.007 us; speedup vs baseline: 1.3535x; 1.0341x over previous
//
#include <hip/hip_runtime.h>

// ---------------------------------------------------------------------------
// cross_entropy_with_hnm_for_one_class_detection
//
// 3 scales: softmax-CE with hard-negative mining (k-th order statistic of
// neg_prob over N=B*H*W) + masked bbox MSE. Output: 3 floats.
//
// R17 lesson: not BW-bound (R16), not TLP-bound (R17) -> barrier-serialized
// control sections dominate. R18: wave-level primitives --
//  - pass1 atomically accumulates pos_tot[s] -> k_cand reads a SCALAR
//    instead of tree-reducing 525 partials (kills ~10 barriers/block);
//  - k_cand's 256-bin scan = single-wave __shfl_up scan (17 barriers -> 2).
// Skeleton unchanged: k_zero -> k_pass1 -> k_cand -> k_select, no fences.
// ---------------------------------------------------------------------------

namespace {
constexpr int HW0 = 25600, HW1 = 6400, HW2 = 1600;
constexpr int N0 = 32 * HW0;  // 819200
constexpr int N1 = 32 * HW1;  // 204800
constexpr int N2 = 32 * HW2;  // 51200

constexpr int LBINS = 256;
constexpr int CAP = 8192;  // candidate capacity per scale

// 2048 elements per block (512 threads x 4 elem)
constexpr int B0 = N0 / 2048, B1 = N1 / 2048, B2 = N2 / 2048;  // 400,100,25
constexpr int NBLK = B0 + B1 + B2;                             // 525

__device__ __forceinline__ void scale_of(int bid, int& s, int& rel, int& lo,
                                         int& hi) {
  if (bid < B0) {
    s = 0; rel = bid; lo = 0; hi = B0;
  } else if (bid < B0 + B1) {
    s = 1; rel = bid - B0; lo = B0; hi = B0 + B1;
  } else {
    s = 2; rel = bid - B0 - B1; lo = B0 + B1; hi = NBLK;
  }
}

__device__ __forceinline__ unsigned int lin_bin(float v) {
  unsigned int b = (unsigned int)(v * 256.0f);
  return b > 255u ? 255u : b;
}
}  // namespace

// ---------------- pass 0: zero control region (~3.3 KB) ---------------------
__global__ __launch_bounds__(256) void k_zero(uint4* __restrict__ p, int n4) {
  for (int i = threadIdx.x; i < n4; i += 256) p[i] = make_uint4(0u, 0u, 0u, 0u);
}

// ------- pass 1: softmax stats, counts, pos-CE, bbox, hist + pos bitmask ----
template <int HW>
__device__ void p1_main(int rel, const float* __restrict__ sc,
                        const float* __restrict__ bb,
                        const float* __restrict__ gl,
                        unsigned int* __restrict__ histS,
                        double* __restrict__ posce_o,
                        double* __restrict__ diff2_o,
                        unsigned int* __restrict__ pcnt_o,
                        unsigned int* __restrict__ pos_totS,
                        unsigned char* __restrict__ pmask_o) {
  __shared__ unsigned int lh[8][LBINS];  // wave-private count hists, 8 KiB
  const int tid = threadIdx.x, wid = tid >> 6;
  for (int i = tid; i < 8 * LBINS; i += 512) ((unsigned int*)lh)[i] = 0u;
  __syncthreads();

  // one quad per thread; all coalesced loads issued before any math
  const int q0 = (rel * 512 + tid) * 4;
  const int bA = q0 / HW, hwA = q0 - bA * HW;
  const float* scA = sc + (size_t)bA * 2 * HW + hwA;
  const float* glA = gl + (size_t)bA * 6 * HW + hwA;
  const float4 s0A = *(const float4*)scA;
  const float4 s1A = *(const float4*)(scA + HW);
  const float4 l0A = *(const float4*)glA;  // pos flag; neg = !pos

  double posce = 0.0, diff2 = 0.0;
  unsigned int pcnt = 0;
  unsigned int pbits = 0u;
  {
    const float* bbq = bb + (size_t)bA * 4 * HW + hwA;
    const float s0a[4] = {s0A.x, s0A.y, s0A.z, s0A.w};
    const float s1a[4] = {s1A.x, s1A.y, s1A.z, s1A.w};
    const float l0a[4] = {l0A.x, l0A.y, l0A.z, l0A.w};
#pragma unroll
    for (int j = 0; j < 4; ++j) {
      const float d = s1a[j] - s0a[j];
      const float t = __expf(-fabsf(d));
      const float l1p = __logf(1.0f + t);  // lse after max-sub
      const bool pos = l0a[j] > 0.5f;
      const float sm1 = ((d >= 0.0f) ? 1.0f : t) / (1.0f + t);
      const float v = pos ? 0.0f : sm1;
      atomicAdd(&lh[wid][lin_bin(v)], 1u);
      if (pos) {
        pbits |= (1u << j);
        pcnt++;
        posce += (double)(l1p + ((d > 0.0f) ? d : 0.0f));  // = -ls0
        float acc = 0.0f;
#pragma unroll
        for (int c = 0; c < 4; ++c) {
          const float dd = glA[(2 + c) * HW + j] - bbq[c * HW + j];
          acc += dd * dd;
        }
        diff2 += (double)acc;
      }
    }
  }
  pmask_o[tid] = (unsigned char)pbits;

  __syncthreads();
  if (tid < LBINS) {  // flush counts: one bin per thread
    unsigned int c = 0;
#pragma unroll
    for (int w = 0; w < 8; ++w) c += lh[w][tid];
    if (c) atomicAdd(&histS[tid], c);
  }

  // reduce partials -> per-block SoA slots + pos_tot atomic
  for (int o = 32; o > 0; o >>= 1) {
    posce += __shfl_down(posce, o, 64);
    diff2 += __shfl_down(diff2, o, 64);
    pcnt += __shfl_down(pcnt, o, 64);
  }
  __shared__ double wa[8], wb[8];
  __shared__ unsigned int wc[8];
  if ((tid & 63) == 0) { wa[wid] = posce; wb[wid] = diff2; wc[wid] = pcnt; }
  __syncthreads();
  if (tid == 0) {
    double a = 0.0, b2 = 0.0;
    unsigned int c = 0;
#pragma unroll
    for (int w = 0; w < 8; ++w) { a += wa[w]; b2 += wb[w]; c += wc[w]; }
    *posce_o = a;
    *diff2_o = b2;
    *pcnt_o = c;
    if (c) atomicAdd(pos_totS, c);  // exact u32 sum; scalar for k_cand
  }
}

__global__ __launch_bounds__(512) void k_pass1(
    const float* sc0, const float* bb0, const float* gl0,
    const float* sc1, const float* bb1, const float* gl1,
    const float* sc2, const float* bb2, const float* gl2,
    unsigned int* hist, double* posce_a, double* diff2_a,
    unsigned int* pcnt_a, unsigned int* pos_tot, unsigned char* pmask) {
  int s, rel, lo, hi;
  scale_of(blockIdx.x, s, rel, lo, hi);
  const int bid = blockIdx.x;
  unsigned char* pm = pmask + (size_t)bid * 512;
  if (s == 0)
    p1_main<HW0>(rel, sc0, bb0, gl0, hist, posce_a + bid, diff2_a + bid,
                 pcnt_a + bid, pos_tot, pm);
  else if (s == 1)
    p1_main<HW1>(rel, sc1, bb1, gl1, hist + LBINS, posce_a + bid,
                 diff2_a + bid, pcnt_a + bid, pos_tot + 1, pm);
  else
    p1_main<HW2>(rel, sc2, bb2, gl2, hist + 2 * LBINS, posce_a + bid,
                 diff2_a + bid, pcnt_a + bid, pos_tot + 2, pm);
}

// --- pass 2: recompute v; ce-below partial; gather in-bin candidates --------
template <int HW, int NS>
__device__ void p2_main(int rel, int s, const float* __restrict__ sc,
                        const unsigned int* __restrict__ pos_tot,
                        const unsigned char* __restrict__ pmask,
                        const unsigned int* __restrict__ hist,
                        double* __restrict__ ceb_o,
                        unsigned int* __restrict__ cand_cnt,
                        unsigned int* __restrict__ cand) {
  const int tid = threadIdx.x, wid = tid >> 6;

  // issue the bulk loads first; they stay in flight across the scan
  const int q0 = (rel * 512 + tid) * 4;
  const int bA = q0 / HW, hwA = q0 - bA * HW;
  const float* scA = sc + (size_t)bA * 2 * HW + hwA;
  const float4 s0A = *(const float4*)scA;
  const float4 s1A = *(const float4*)(scA + HW);
  const unsigned int pbits = pmask[tid];  // 4 pos bits for this thread

  // k from the scalar pos total (no tree reduce)
  const unsigned int pos = pos_tot[s];
  const unsigned int neg = (unsigned int)NS - pos;
  const unsigned long long k10 = 10ull * (unsigned long long)pos;
  const unsigned int k =
      (k10 < (unsigned long long)neg) ? (unsigned int)k10 : neg;

  // sel_bin via single-wave shfl scan: lane i owns bins [4i, 4i+4)
  __shared__ unsigned int sh_selb;
  if (tid < 64) {
    unsigned int c4[4];
    unsigned int own = 0;
#pragma unroll
    for (int i = 0; i < 4; ++i) {
      c4[i] = hist[s * LBINS + tid * 4 + i];
      own += c4[i];
    }
    unsigned int incl = own;
#pragma unroll
    for (int o = 1; o < 64; o <<= 1) {
      const unsigned int t = __shfl_up(incl, o, 64);
      if (tid >= o) incl += t;
    }
    const unsigned int excl = incl - own;
    if (own && k >= excl && k < incl) {  // unique winner lane
      unsigned int run = excl;
      unsigned int sel = tid * 4 + 3;
#pragma unroll
      for (int i = 0; i < 4; ++i) {
        if (run + c4[i] > k) { sel = tid * 4 + i; break; }
        run += c4[i];
      }
      sh_selb = sel;
    }
  }
  __syncthreads();

  // recompute v (bitwise == pass1), sum ce for bins < selb, gather in-bin
  __shared__ unsigned int cbuf[512];
  __shared__ unsigned int ccnt, cbase;
  if (tid == 0) ccnt = 0u;
  __syncthreads();
  const unsigned int bsel = sh_selb;
  double ceb = 0.0;
  {
    const float s0a[4] = {s0A.x, s0A.y, s0A.z, s0A.w};
    const float s1a[4] = {s1A.x, s1A.y, s1A.z, s1A.w};
#pragma unroll
    for (int j = 0; j < 4; ++j) {
      if (pbits & (1u << j)) continue;  // pos: no neg-CE
      const float d = s1a[j] - s0a[j];
      const float t = __expf(-fabsf(d));
      const float v = ((d >= 0.0f) ? 1.0f : t) / (1.0f + t);
      const unsigned int bin = lin_bin(v);
      if (bin < bsel) {
        ceb += (double)(__logf(1.0f + t) + ((d >= 0.0f) ? 0.0f : -d));
      } else if (bin == bsel) {
        const unsigned int sl = atomicAdd(&ccnt, 1u);
        if (sl < 512u) {
          cbuf[sl] = __float_as_uint(v);
        } else {  // overflow fallback (rare)
          const unsigned int g2 = atomicAdd(&cand_cnt[s], 1u);
          if (g2 < (unsigned)CAP) cand[s * CAP + g2] = __float_as_uint(v);
        }
      }
    }
  }
  __syncthreads();
  if (tid == 0) {
    const unsigned int n = min(ccnt, 512u);
    cbase = n ? atomicAdd(&cand_cnt[s], n) : 0u;
  }
  __syncthreads();
  {
    const unsigned int n = min(ccnt, 512u);
    for (unsigned int i = tid; i < n; i += 512) {
      const unsigned int idx = cbase + i;
      if (idx < (unsigned)CAP) cand[s * CAP + idx] = cbuf[i];
    }
  }

  // reduce ceb -> per-block slot
  for (int o = 32; o > 0; o >>= 1) ceb += __shfl_down(ceb, o, 64);
  __shared__ double wv[8];
  if ((tid & 63) == 0) wv[wid] = ceb;
  __syncthreads();
  if (tid == 0) {
    double e = 0.0;
#pragma unroll
    for (int w = 0; w < 8; ++w) e += wv[w];
    *ceb_o = e;
  }
}

__global__ __launch_bounds__(512) void k_cand(
    const float* sc0, const float* sc1, const float* sc2,
    const unsigned int* __restrict__ pos_tot,
    const unsigned char* __restrict__ pmask,
    const unsigned int* __restrict__ hist, double* __restrict__ ceb_a,
    unsigned int* __restrict__ cand_cnt, unsigned int* __restrict__ cand) {
  int s, rel, lo, hi;
  scale_of(blockIdx.x, s, rel, lo, hi);
  const int bid = blockIdx.x;
  const unsigned char* pm = pmask + (size_t)bid * 512;
  if (s == 0)
    p2_main<HW0, N0>(rel, 0, sc0, pos_tot, pm, hist, ceb_a + bid, cand_cnt,
                     cand);
  else if (s == 1)
    p2_main<HW1, N1>(rel, 1, sc1, pos_tot, pm, hist, ceb_a + bid, cand_cnt,
                     cand);
  else
    p2_main<HW2, N2>(rel, 2, sc2, pos_tot, pm, hist, ceb_a + bid, cand_cnt,
                     cand);
}

// ------- pass 3: 3 blocks -- reduce + scan + radix select + finalize --------
__global__ __launch_bounds__(256) void k_select(
    const double* __restrict__ posce_a, const double* __restrict__ diff2_a,
    const double* __restrict__ ceb_a, const unsigned int* __restrict__ pos_tot,
    const unsigned int* __restrict__ hist,
    const unsigned int* __restrict__ cand_cnt,
    const unsigned int* __restrict__ cand, float* __restrict__ out) {
  const int s = blockIdx.x;
  const int tid = threadIdx.x;
  const int lo = (s == 0) ? 0 : (s == 1) ? B0 : B0 + B1;
  const int hi = (s == 0) ? B0 : (s == 1) ? B0 + B1 : NBLK;
  const unsigned int NS =
      (s == 0) ? (unsigned)N0 : (s == 1) ? (unsigned)N1 : (unsigned)N2;

  __shared__ double sda[256], sdb[256], sdc[256];
  {
    double a = 0.0, b2 = 0.0, e = 0.0;
    for (int i = lo + tid; i < hi; i += 256) {
      a += posce_a[i]; b2 += diff2_a[i]; e += ceb_a[i];
    }
    sda[tid] = a; sdb[tid] = b2; sdc[tid] = e;
  }
  __syncthreads();
  for (int o = 128; o > 0; o >>= 1) {
    if (tid < o) {
      sda[tid] += sda[tid + o]; sdb[tid] += sdb[tid + o];
      sdc[tid] += sdc[tid + o];
    }
    __syncthreads();
  }
  __shared__ double sh_posce, sh_diff2, sh_ceb;
  __shared__ unsigned int sh_pcnt, sh_k;
  if (tid == 0) {
    sh_posce = sda[0];
    sh_diff2 = sdb[0];
    sh_ceb = sdc[0];
    const unsigned int pos = pos_tot[s];
    sh_pcnt = pos;
    const unsigned int neg = NS - pos;
    const unsigned long long k10 = 10ull * (unsigned long long)pos;
    sh_k = (k10 < (unsigned long long)neg) ? (unsigned int)k10 : neg;
  }
  __syncthreads();

  // count-only 256-bin scan -> selb, selr
  __shared__ unsigned int partC[256];
  __shared__ unsigned int sh_selb, sh_selr;
  const unsigned int ownC = hist[s * LBINS + tid];
  partC[tid] = ownC;
  __syncthreads();
  for (int o = 1; o < 256; o <<= 1) {
    const unsigned int aC = (tid >= o) ? partC[tid - o] : 0u;
    __syncthreads();
    partC[tid] += aC;
    __syncthreads();
  }
  {
    const unsigned int k = sh_k;
    const unsigned int inclC = partC[tid];
    const unsigned int exclC = inclC - ownC;
    if (ownC && k >= exclC && k < inclC) {
      sh_selb = (unsigned int)tid;
      sh_selr = k - exclC;
    }
  }
  __syncthreads();

  // exact radix select over candidates
  const unsigned int n = min(cand_cnt[s], (unsigned int)CAP);
  const unsigned int* lst = cand + s * CAP;
  __shared__ unsigned int dh[256];
  __shared__ unsigned int shp, shr, sh_w8, sh_nr;
  if (tid == 0) {
    shr = sh_selr;
    // bins >=1 lie within one binade -> candidates share bits 31:24
    shp = (sh_selb >= 1u) ? (lst[0] & 0xFF000000u) : 0u;
  }
  __syncthreads();
  const int r0 = (sh_selb >= 1u) ? 1 : 0;
  for (int round = r0; round < 4; ++round) {
    const int shift = 24 - 8 * round;
    dh[tid] = 0u;
    __syncthreads();
    const unsigned int pref = shp;
    for (unsigned int i = tid; i < n; i += 256) {
      const unsigned int v = lst[i];
      const bool match =
          (round == 0) || ((v >> (shift + 8)) == (pref >> (shift + 8)));
      if (match) atomicAdd(&dh[(v >> shift) & 255u], 1u);
    }
    __syncthreads();
    const unsigned int own = dh[tid];
    for (int o = 1; o < 256; o <<= 1) {  // inclusive scan in place
      const unsigned int add = (tid >= o) ? dh[tid - o] : 0u;
      __syncthreads();
      dh[tid] += add;
      __syncthreads();
    }
    const unsigned int incl = dh[tid];
    const unsigned int excl = incl - own;
    const unsigned int k = shr;
    if (own && k >= excl && k < incl) {
      sh_w8 = (unsigned int)tid;
      sh_nr = k - excl;
    }
    __syncthreads();
    if (tid == 0) {
      shp = pref | (sh_w8 << shift);
      shr = sh_nr;
    }
    __syncthreads();
  }
  const float thr = __uint_as_float(shp);

  // in-bin CE: candidates with 0 < v <= thr
  double acc = 0.0;
  for (unsigned int i = tid; i < n; i += 256) {
    const float v = __uint_as_float(lst[i]);
    if (v > 0.0f && v <= thr) acc += (double)(-__logf(v));
  }
  sda[tid] = acc;
  __syncthreads();
  for (int o = 128; o > 0; o >>= 1) {
    if (tid < o) sda[tid] += sda[tid + o];
    __syncthreads();
  }
  if (tid == 0) {
    const double Ns = (double)NS;
    const double W = (s == 0) ? 160.0 : (s == 1) ? 80.0 : 40.0;
    const double ls = (sh_posce + sh_ceb + sda[0]) / (2.0 * Ns);
    const double lb = (sh_diff2 / W) / (4.0 * (double)sh_pcnt);
    out[s] = (float)(ls + lb);
  }
}

extern "C" void kernel_launch(void* const* d_in, const int* in_sizes, int n_in,
                              void* d_out, int out_size, void* d_ws,
                              size_t ws_size, hipStream_t stream) {
  const float* sc0 = (const float*)d_in[0];
  const float* bb0 = (const float*)d_in[1];
  const float* gl0 = (const float*)d_in[3];
  const float* sc1 = (const float*)d_in[4];
  const float* bb1 = (const float*)d_in[5];
  const float* gl1 = (const float*)d_in[7];
  const float* sc2 = (const float*)d_in[8];
  const float* bb2 = (const float*)d_in[9];
  const float* gl2 = (const float*)d_in[11];

  char* ws = (char*)d_ws;
  unsigned int* hist = (unsigned int*)ws;              // 3*256 u32
  unsigned int* cand_cnt = hist + 3 * LBINS;           // 4 u32
  unsigned int* pos_tot = cand_cnt + 4;                // 4 u32
  size_t zbytes = (size_t)3 * LBINS * 4 + 32;          // zeroed region
  zbytes = (zbytes + 255) & ~(size_t)255;
  size_t off = zbytes;
  double* posce_a = (double*)(ws + off);  off += (size_t)NBLK * 8;
  double* diff2_a = (double*)(ws + off);  off += (size_t)NBLK * 8;
  double* ceb_a = (double*)(ws + off);    off += (size_t)NBLK * 8;
  unsigned int* pcnt_a = (unsigned int*)(ws + off);  off += (size_t)NBLK * 4;
  off = (off + 255) & ~(size_t)255;
  unsigned char* pmask = (unsigned char*)(ws + off);   // NBLK*512 u8
  off += (size_t)NBLK * 512;
  off = (off + 255) & ~(size_t)255;
  unsigned int* cand = (unsigned int*)(ws + off);      // 3*CAP u32

  k_zero<<<dim3(1), dim3(256), 0, stream>>>((uint4*)d_ws, (int)(zbytes >> 4));
  k_pass1<<<dim3(NBLK), dim3(512), 0, stream>>>(sc0, bb0, gl0, sc1, bb1, gl1,
                                                sc2, bb2, gl2, hist, posce_a,
                                                diff2_a, pcnt_a, pos_tot,
                                                pmask);
  k_cand<<<dim3(NBLK), dim3(512), 0, stream>>>(sc0, sc1, sc2, pos_tot, pmask,
                                               hist, ceb_a, cand_cnt, cand);
  k_select<<<dim3(3), dim3(256), 0, stream>>>(posce_a, diff2_a, ceb_a,
                                              pos_tot, hist, cand_cnt, cand,
                                              (float*)d_out);
}

// Round 19
// 47.542 us; speedup vs baseline: 1.3667x; 1.0098x over previous
//
#include <hip/hip_runtime.h>

// ---------------------------------------------------------------------------
// cross_entropy_with_hnm_for_one_class_detection
//
// 3 scales: softmax-CE with hard-negative mining (k-th order statistic of
// neg_prob over N=B*H*W) + masked bbox MSE. Output: 3 floats.
//
// R18 model: pass1 was gather-latency-bound (~99% of waves stall on the
// divergent 8-line bbox gather, issued late, ~4 waves/SIMD to hide it);
// k_cand is pure-coalesced with idle latency capacity. R19: move diff2 to
// k_cand; issue the pos-gathers FIRST there (hidden under scan + ce work).
// pass1 becomes pure streaming. Same per-thread/per-block f64 accumulation
// order -> bitwise-identical results. Skeleton: k_zero -> k_pass1 ->
// k_cand -> k_select, no fences.
// ---------------------------------------------------------------------------

namespace {
constexpr int HW0 = 25600, HW1 = 6400, HW2 = 1600;
constexpr int N0 = 32 * HW0;  // 819200
constexpr int N1 = 32 * HW1;  // 204800
constexpr int N2 = 32 * HW2;  // 51200

constexpr int LBINS = 256;
constexpr int CAP = 8192;  // candidate capacity per scale

// 2048 elements per block (512 threads x 4 elem)
constexpr int B0 = N0 / 2048, B1 = N1 / 2048, B2 = N2 / 2048;  // 400,100,25
constexpr int NBLK = B0 + B1 + B2;                             // 525

__device__ __forceinline__ void scale_of(int bid, int& s, int& rel, int& lo,
                                         int& hi) {
  if (bid < B0) {
    s = 0; rel = bid; lo = 0; hi = B0;
  } else if (bid < B0 + B1) {
    s = 1; rel = bid - B0; lo = B0; hi = B0 + B1;
  } else {
    s = 2; rel = bid - B0 - B1; lo = B0 + B1; hi = NBLK;
  }
}

__device__ __forceinline__ unsigned int lin_bin(float v) {
  unsigned int b = (unsigned int)(v * 256.0f);
  return b > 255u ? 255u : b;
}
}  // namespace

// ---------------- pass 0: zero control region (~3.3 KB) ---------------------
__global__ __launch_bounds__(256) void k_zero(uint4* __restrict__ p, int n4) {
  for (int i = threadIdx.x; i < n4; i += 256) p[i] = make_uint4(0u, 0u, 0u, 0u);
}

// ------- pass 1: PURE STREAMING: softmax stats, counts, pos-CE, hist --------
template <int HW>
__device__ void p1_main(int rel, const float* __restrict__ sc,
                        const float* __restrict__ gl,
                        unsigned int* __restrict__ histS,
                        double* __restrict__ posce_o,
                        unsigned int* __restrict__ pcnt_o,
                        unsigned int* __restrict__ pos_totS,
                        unsigned char* __restrict__ pmask_o) {
  __shared__ unsigned int lh[8][LBINS];  // wave-private count hists, 8 KiB
  const int tid = threadIdx.x, wid = tid >> 6;
  for (int i = tid; i < 8 * LBINS; i += 512) ((unsigned int*)lh)[i] = 0u;
  __syncthreads();

  // one quad per thread; all coalesced loads issued before any math
  const int q0 = (rel * 512 + tid) * 4;
  const int bA = q0 / HW, hwA = q0 - bA * HW;
  const float* scA = sc + (size_t)bA * 2 * HW + hwA;
  const float4 s0A = *(const float4*)scA;
  const float4 s1A = *(const float4*)(scA + HW);
  const float4 l0A = *(const float4*)(gl + (size_t)bA * 6 * HW + hwA);

  double posce = 0.0;
  unsigned int pcnt = 0;
  unsigned int pbits = 0u;
  {
    const float s0a[4] = {s0A.x, s0A.y, s0A.z, s0A.w};
    const float s1a[4] = {s1A.x, s1A.y, s1A.z, s1A.w};
    const float l0a[4] = {l0A.x, l0A.y, l0A.z, l0A.w};
#pragma unroll
    for (int j = 0; j < 4; ++j) {
      const float d = s1a[j] - s0a[j];
      const float t = __expf(-fabsf(d));
      const float l1p = __logf(1.0f + t);  // lse after max-sub
      const bool pos = l0a[j] > 0.5f;
      const float sm1 = ((d >= 0.0f) ? 1.0f : t) / (1.0f + t);
      const float v = pos ? 0.0f : sm1;
      atomicAdd(&lh[wid][lin_bin(v)], 1u);
      if (pos) {
        pbits |= (1u << j);
        pcnt++;
        posce += (double)(l1p + ((d > 0.0f) ? d : 0.0f));  // = -ls0
      }
    }
  }
  pmask_o[tid] = (unsigned char)pbits;

  __syncthreads();
  if (tid < LBINS) {  // flush counts: one bin per thread
    unsigned int c = 0;
#pragma unroll
    for (int w = 0; w < 8; ++w) c += lh[w][tid];
    if (c) atomicAdd(&histS[tid], c);
  }

  // reduce partials -> per-block SoA slots + pos_tot atomic
  for (int o = 32; o > 0; o >>= 1) {
    posce += __shfl_down(posce, o, 64);
    pcnt += __shfl_down(pcnt, o, 64);
  }
  __shared__ double wa[8];
  __shared__ unsigned int wc[8];
  if ((tid & 63) == 0) { wa[wid] = posce; wc[wid] = pcnt; }
  __syncthreads();
  if (tid == 0) {
    double a = 0.0;
    unsigned int c = 0;
#pragma unroll
    for (int w = 0; w < 8; ++w) { a += wa[w]; c += wc[w]; }
    *posce_o = a;
    *pcnt_o = c;
    if (c) atomicAdd(pos_totS, c);  // exact u32 sum; scalar for k_cand
  }
}

__global__ __launch_bounds__(512) void k_pass1(
    const float* sc0, const float* gl0, const float* sc1, const float* gl1,
    const float* sc2, const float* gl2, unsigned int* hist, double* posce_a,
    unsigned int* pcnt_a, unsigned int* pos_tot, unsigned char* pmask) {
  int s, rel, lo, hi;
  scale_of(blockIdx.x, s, rel, lo, hi);
  const int bid = blockIdx.x;
  unsigned char* pm = pmask + (size_t)bid * 512;
  if (s == 0)
    p1_main<HW0>(rel, sc0, gl0, hist, posce_a + bid, pcnt_a + bid, pos_tot,
                 pm);
  else if (s == 1)
    p1_main<HW1>(rel, sc1, gl1, hist + LBINS, posce_a + bid, pcnt_a + bid,
                 pos_tot + 1, pm);
  else
    p1_main<HW2>(rel, sc2, gl2, hist + 2 * LBINS, posce_a + bid,
                 pcnt_a + bid, pos_tot + 2, pm);
}

// --- pass 2: pos-gather diff2 (issued FIRST) + ce-below + candidates --------
template <int HW, int NS>
__device__ void p2_main(int rel, int s, const float* __restrict__ sc,
                        const float* __restrict__ bb,
                        const float* __restrict__ gl,
                        const unsigned int* __restrict__ pos_tot,
                        const unsigned char* __restrict__ pmask,
                        const unsigned int* __restrict__ hist,
                        double* __restrict__ ceb_o,
                        double* __restrict__ diff2_o,
                        unsigned int* __restrict__ cand_cnt,
                        unsigned int* __restrict__ cand) {
  const int tid = threadIdx.x, wid = tid >> 6;

  // issue the coalesced loads + pmask first
  const int q0 = (rel * 512 + tid) * 4;
  const int bA = q0 / HW, hwA = q0 - bA * HW;
  const float* scA = sc + (size_t)bA * 2 * HW + hwA;
  const float4 s0A = *(const float4*)scA;
  const float4 s1A = *(const float4*)(scA + HW);
  const unsigned int pbits = pmask[tid];  // 4 pos bits for this thread

  // issue ALL pos-gather loads up-front; consumed at the very end so their
  // ~400-900 cycle latency hides under the scan + ce/candidate work below
  float gv[16], bv[16];
  {
    const float* glq = gl + (size_t)bA * 6 * HW + hwA;
    const float* bbq = bb + (size_t)bA * 4 * HW + hwA;
#pragma unroll
    for (int j = 0; j < 4; ++j) {
      if (pbits & (1u << j)) {
#pragma unroll
        for (int c = 0; c < 4; ++c) {
          gv[j * 4 + c] = glq[(2 + c) * HW + j];
          bv[j * 4 + c] = bbq[c * HW + j];
        }
      }
    }
  }

  // k from the scalar pos total (no tree reduce)
  const unsigned int pos = pos_tot[s];
  const unsigned int neg = (unsigned int)NS - pos;
  const unsigned long long k10 = 10ull * (unsigned long long)pos;
  const unsigned int k =
      (k10 < (unsigned long long)neg) ? (unsigned int)k10 : neg;

  // sel_bin via single-wave shfl scan: lane i owns bins [4i, 4i+4)
  __shared__ unsigned int sh_selb;
  if (tid < 64) {
    unsigned int c4[4];
    unsigned int own = 0;
#pragma unroll
    for (int i = 0; i < 4; ++i) {
      c4[i] = hist[s * LBINS + tid * 4 + i];
      own += c4[i];
    }
    unsigned int incl = own;
#pragma unroll
    for (int o = 1; o < 64; o <<= 1) {
      const unsigned int t = __shfl_up(incl, o, 64);
      if (tid >= o) incl += t;
    }
    const unsigned int excl = incl - own;
    if (own && k >= excl && k < incl) {  // unique winner lane
      unsigned int run = excl;
      unsigned int sel = tid * 4 + 3;
#pragma unroll
      for (int i = 0; i < 4; ++i) {
        if (run + c4[i] > k) { sel = tid * 4 + i; break; }
        run += c4[i];
      }
      sh_selb = sel;
    }
  }
  __syncthreads();

  // recompute v (bitwise == pass1), sum ce for bins < selb, gather in-bin
  __shared__ unsigned int cbuf[512];
  __shared__ unsigned int ccnt, cbase;
  if (tid == 0) ccnt = 0u;
  __syncthreads();
  const unsigned int bsel = sh_selb;
  double ceb = 0.0;
  {
    const float s0a[4] = {s0A.x, s0A.y, s0A.z, s0A.w};
    const float s1a[4] = {s1A.x, s1A.y, s1A.z, s1A.w};
#pragma unroll
    for (int j = 0; j < 4; ++j) {
      if (pbits & (1u << j)) continue;  // pos: no neg-CE
      const float d = s1a[j] - s0a[j];
      const float t = __expf(-fabsf(d));
      const float v = ((d >= 0.0f) ? 1.0f : t) / (1.0f + t);
      const unsigned int bin = lin_bin(v);
      if (bin < bsel) {
        ceb += (double)(__logf(1.0f + t) + ((d >= 0.0f) ? 0.0f : -d));
      } else if (bin == bsel) {
        const unsigned int sl = atomicAdd(&ccnt, 1u);
        if (sl < 512u) {
          cbuf[sl] = __float_as_uint(v);
        } else {  // overflow fallback (rare)
          const unsigned int g2 = atomicAdd(&cand_cnt[s], 1u);
          if (g2 < (unsigned)CAP) cand[s * CAP + g2] = __float_as_uint(v);
        }
      }
    }
  }
  __syncthreads();
  if (tid == 0) {
    const unsigned int n = min(ccnt, 512u);
    cbase = n ? atomicAdd(&cand_cnt[s], n) : 0u;
  }
  __syncthreads();
  {
    const unsigned int n = min(ccnt, 512u);
    for (unsigned int i = tid; i < n; i += 512) {
      const unsigned int idx = cbase + i;
      if (idx < (unsigned)CAP) cand[s * CAP + idx] = cbuf[i];
    }
  }

  // consume gathers: diff2 (same per-thread j order as R18's pass1)
  double diff2 = 0.0;
#pragma unroll
  for (int j = 0; j < 4; ++j) {
    if (pbits & (1u << j)) {
      float acc = 0.0f;
#pragma unroll
      for (int c = 0; c < 4; ++c) {
        const float dd = gv[j * 4 + c] - bv[j * 4 + c];
        acc += dd * dd;
      }
      diff2 += (double)acc;
    }
  }

  // reduce ceb + diff2 -> per-block slots
  for (int o = 32; o > 0; o >>= 1) {
    ceb += __shfl_down(ceb, o, 64);
    diff2 += __shfl_down(diff2, o, 64);
  }
  __shared__ double wv[8], wd[8];
  if ((tid & 63) == 0) { wv[wid] = ceb; wd[wid] = diff2; }
  __syncthreads();
  if (tid == 0) {
    double e = 0.0, d2 = 0.0;
#pragma unroll
    for (int w = 0; w < 8; ++w) { e += wv[w]; d2 += wd[w]; }
    *ceb_o = e;
    *diff2_o = d2;
  }
}

__global__ __launch_bounds__(512) void k_cand(
    const float* sc0, const float* bb0, const float* gl0,
    const float* sc1, const float* bb1, const float* gl1,
    const float* sc2, const float* bb2, const float* gl2,
    const unsigned int* __restrict__ pos_tot,
    const unsigned char* __restrict__ pmask,
    const unsigned int* __restrict__ hist, double* __restrict__ ceb_a,
    double* __restrict__ diff2_a, unsigned int* __restrict__ cand_cnt,
    unsigned int* __restrict__ cand) {
  int s, rel, lo, hi;
  scale_of(blockIdx.x, s, rel, lo, hi);
  const int bid = blockIdx.x;
  const unsigned char* pm = pmask + (size_t)bid * 512;
  if (s == 0)
    p2_main<HW0, N0>(rel, 0, sc0, bb0, gl0, pos_tot, pm, hist, ceb_a + bid,
                     diff2_a + bid, cand_cnt, cand);
  else if (s == 1)
    p2_main<HW1, N1>(rel, 1, sc1, bb1, gl1, pos_tot, pm, hist, ceb_a + bid,
                     diff2_a + bid, cand_cnt, cand);
  else
    p2_main<HW2, N2>(rel, 2, sc2, bb2, gl2, pos_tot, pm, hist, ceb_a + bid,
                     diff2_a + bid, cand_cnt, cand);
}

// ------- pass 3: 3 blocks -- reduce + scan + radix select + finalize --------
__global__ __launch_bounds__(256) void k_select(
    const double* __restrict__ posce_a, const double* __restrict__ diff2_a,
    const double* __restrict__ ceb_a, const unsigned int* __restrict__ pos_tot,
    const unsigned int* __restrict__ hist,
    const unsigned int* __restrict__ cand_cnt,
    const unsigned int* __restrict__ cand, float* __restrict__ out) {
  const int s = blockIdx.x;
  const int tid = threadIdx.x;
  const int lo = (s == 0) ? 0 : (s == 1) ? B0 : B0 + B1;
  const int hi = (s == 0) ? B0 : (s == 1) ? B0 + B1 : NBLK;
  const unsigned int NS =
      (s == 0) ? (unsigned)N0 : (s == 1) ? (unsigned)N1 : (unsigned)N2;

  __shared__ double sda[256], sdb[256], sdc[256];
  {
    double a = 0.0, b2 = 0.0, e = 0.0;
    for (int i = lo + tid; i < hi; i += 256) {
      a += posce_a[i]; b2 += diff2_a[i]; e += ceb_a[i];
    }
    sda[tid] = a; sdb[tid] = b2; sdc[tid] = e;
  }
  __syncthreads();
  for (int o = 128; o > 0; o >>= 1) {
    if (tid < o) {
      sda[tid] += sda[tid + o]; sdb[tid] += sdb[tid + o];
      sdc[tid] += sdc[tid + o];
    }
    __syncthreads();
  }
  __shared__ double sh_posce, sh_diff2, sh_ceb;
  __shared__ unsigned int sh_pcnt, sh_k;
  if (tid == 0) {
    sh_posce = sda[0];
    sh_diff2 = sdb[0];
    sh_ceb = sdc[0];
    const unsigned int pos = pos_tot[s];
    sh_pcnt = pos;
    const unsigned int neg = NS - pos;
    const unsigned long long k10 = 10ull * (unsigned long long)pos;
    sh_k = (k10 < (unsigned long long)neg) ? (unsigned int)k10 : neg;
  }
  __syncthreads();

  // count-only 256-bin scan -> selb, selr
  __shared__ unsigned int partC[256];
  __shared__ unsigned int sh_selb, sh_selr;
  const unsigned int ownC = hist[s * LBINS + tid];
  partC[tid] = ownC;
  __syncthreads();
  for (int o = 1; o < 256; o <<= 1) {
    const unsigned int aC = (tid >= o) ? partC[tid - o] : 0u;
    __syncthreads();
    partC[tid] += aC;
    __syncthreads();
  }
  {
    const unsigned int k = sh_k;
    const unsigned int inclC = partC[tid];
    const unsigned int exclC = inclC - ownC;
    if (ownC && k >= exclC && k < inclC) {
      sh_selb = (unsigned int)tid;
      sh_selr = k - exclC;
    }
  }
  __syncthreads();

  // exact radix select over candidates
  const unsigned int n = min(cand_cnt[s], (unsigned int)CAP);
  const unsigned int* lst = cand + s * CAP;
  __shared__ unsigned int dh[256];
  __shared__ unsigned int shp, shr, sh_w8, sh_nr;
  if (tid == 0) {
    shr = sh_selr;
    // bins >=1 lie within one binade -> candidates share bits 31:24
    shp = (sh_selb >= 1u) ? (lst[0] & 0xFF000000u) : 0u;
  }
  __syncthreads();
  const int r0 = (sh_selb >= 1u) ? 1 : 0;
  for (int round = r0; round < 4; ++round) {
    const int shift = 24 - 8 * round;
    dh[tid] = 0u;
    __syncthreads();
    const unsigned int pref = shp;
    for (unsigned int i = tid; i < n; i += 256) {
      const unsigned int v = lst[i];
      const bool match =
          (round == 0) || ((v >> (shift + 8)) == (pref >> (shift + 8)));
      if (match) atomicAdd(&dh[(v >> shift) & 255u], 1u);
    }
    __syncthreads();
    const unsigned int own = dh[tid];
    for (int o = 1; o < 256; o <<= 1) {  // inclusive scan in place
      const unsigned int add = (tid >= o) ? dh[tid - o] : 0u;
      __syncthreads();
      dh[tid] += add;
      __syncthreads();
    }
    const unsigned int incl = dh[tid];
    const unsigned int excl = incl - own;
    const unsigned int k = shr;
    if (own && k >= excl && k < incl) {
      sh_w8 = (unsigned int)tid;
      sh_nr = k - excl;
    }
    __syncthreads();
    if (tid == 0) {
      shp = pref | (sh_w8 << shift);
      shr = sh_nr;
    }
    __syncthreads();
  }
  const float thr = __uint_as_float(shp);

  // in-bin CE: candidates with 0 < v <= thr
  double acc = 0.0;
  for (unsigned int i = tid; i < n; i += 256) {
    const float v = __uint_as_float(lst[i]);
    if (v > 0.0f && v <= thr) acc += (double)(-__logf(v));
  }
  sda[tid] = acc;
  __syncthreads();
  for (int o = 128; o > 0; o >>= 1) {
    if (tid < o) sda[tid] += sda[tid + o];
    __syncthreads();
  }
  if (tid == 0) {
    const double Ns = (double)NS;
    const double W = (s == 0) ? 160.0 : (s == 1) ? 80.0 : 40.0;
    const double ls = (sh_posce + sh_ceb + sda[0]) / (2.0 * Ns);
    const double lb = (sh_diff2 / W) / (4.0 * (double)sh_pcnt);
    out[s] = (float)(ls + lb);
  }
}

extern "C" void kernel_launch(void* const* d_in, const int* in_sizes, int n_in,
                              void* d_out, int out_size, void* d_ws,
                              size_t ws_size, hipStream_t stream) {
  const float* sc0 = (const float*)d_in[0];
  const float* bb0 = (const float*)d_in[1];
  const float* gl0 = (const float*)d_in[3];
  const float* sc1 = (const float*)d_in[4];
  const float* bb1 = (const float*)d_in[5];
  const float* gl1 = (const float*)d_in[7];
  const float* sc2 = (const float*)d_in[8];
  const float* bb2 = (const float*)d_in[9];
  const float* gl2 = (const float*)d_in[11];

  char* ws = (char*)d_ws;
  unsigned int* hist = (unsigned int*)ws;              // 3*256 u32
  unsigned int* cand_cnt = hist + 3 * LBINS;           // 4 u32
  unsigned int* pos_tot = cand_cnt + 4;                // 4 u32
  size_t zbytes = (size_t)3 * LBINS * 4 + 32;          // zeroed region
  zbytes = (zbytes + 255) & ~(size_t)255;
  size_t off = zbytes;
  double* posce_a = (double*)(ws + off);  off += (size_t)NBLK * 8;
  double* diff2_a = (double*)(ws + off);  off += (size_t)NBLK * 8;
  double* ceb_a = (double*)(ws + off);    off += (size_t)NBLK * 8;
  unsigned int* pcnt_a = (unsigned int*)(ws + off);  off += (size_t)NBLK * 4;
  off = (off + 255) & ~(size_t)255;
  unsigned char* pmask = (unsigned char*)(ws + off);   // NBLK*512 u8
  off += (size_t)NBLK * 512;
  off = (off + 255) & ~(size_t)255;
  unsigned int* cand = (unsigned int*)(ws + off);      // 3*CAP u32

  k_zero<<<dim3(1), dim3(256), 0, stream>>>((uint4*)d_ws, (int)(zbytes >> 4));
  k_pass1<<<dim3(NBLK), dim3(512), 0, stream>>>(sc0, gl0, sc1, gl1, sc2, gl2,
                                                hist, posce_a, pcnt_a,
                                                pos_tot, pmask);
  k_cand<<<dim3(NBLK), dim3(512), 0, stream>>>(sc0, bb0, gl0, sc1, bb1, gl1,
                                               sc2, bb2, gl2, pos_tot, pmask,
                                               hist, ceb_a, diff2_a, cand_cnt,
                                               cand);
  k_select<<<dim3(3), dim3(256), 0, stream>>>(posce_a, diff2_a, ceb_a,
                                              pos_tot, hist, cand_cnt, cand,
                                              (float*)d_out);
}